// Round 18
// baseline (472.681 us; speedup 1.0000x reference)
//
#include <hip/hip_runtime.h>
#include <hip/hip_bf16.h>
#include <math.h>

#define B_ 8
#define C_ 128
#define H_ 64
#define W_ 64
#define HW_ 4096
#define HEADS_ 8
#define CH_ 16
#define HID_ 512

typedef unsigned short ushort_t;
struct __attribute__((aligned(8))) us4 { ushort_t x, y, z, w; };

typedef __attribute__((ext_vector_type(8))) short bf16x8;
typedef __attribute__((ext_vector_type(4))) float f32x4;

__device__ __forceinline__ float bf2f(ushort_t u) {
  return __uint_as_float(((unsigned int)u) << 16);
}
__device__ __forceinline__ ushort_t f2bu(float f) {
  __hip_bfloat16 h = __float2bfloat16(f);
  return *reinterpret_cast<ushort_t*>(&h);
}
__device__ __forceinline__ float toF(float v) { return v; }
__device__ __forceinline__ float toF(ushort_t v) { return bf2f(v); }
__device__ __forceinline__ void storeF(float* p, float v) { *p = v; }
__device__ __forceinline__ void storeF(ushort_t* p, float v) { *p = f2bu(v); }

// tanh-GELU: max dev from exact erf-GELU ~1e-3, straight-line
__device__ __forceinline__ float gelu_t(float x) {
  float z = 0.7978845608f * fmaf(0.044715f * x, x * x, x);
  float e = __expf(2.f * z);
  float th = 1.f - 2.f / (e + 1.f);
  return 0.5f * x * (1.f + th);
}

// ---------------- LayerNorm over channel dim (bf16 out) ----------------
__global__ __launch_bounds__(256) void ln_ch(const float* __restrict__ x,
                                             const float* __restrict__ w,
                                             const float* __restrict__ b,
                                             ushort_t* __restrict__ out) {
  int p = blockIdx.x * 256 + threadIdx.x;  // over B*HW
  int bi = p >> 12;
  int pos = p & (HW_ - 1);
  const float* xb = x + (size_t)bi * C_ * HW_ + pos;
  float s = 0.f, ss = 0.f;
  for (int c = 0; c < C_; c++) {
    float v = xb[(size_t)c * HW_];
    s += v;
    ss = fmaf(v, v, ss);
  }
  float mu = s * (1.f / C_);
  float var = ss * (1.f / C_) - mu * mu;
  float inv = rsqrtf(var + 1e-5f);
  ushort_t* ob = out + (size_t)bi * C_ * HW_ + pos;
  for (int c = 0; c < C_; c++) {
    ob[(size_t)c * HW_] = f2bu((xb[(size_t)c * HW_] - mu) * inv * w[c] + b[c]);
  }
}

// ---------------- weight prep: fp32 -> bf16, all six matrices ----------------
__global__ __launch_bounds__(256) void cvt_w(const float* __restrict__ wq,
                                             const float* __restrict__ wk,
                                             const float* __restrict__ wv,
                                             const float* __restrict__ apo,
                                             const float* __restrict__ fin,
                                             const float* __restrict__ fpo,
                                             ushort_t* __restrict__ dst) {
  int id = blockIdx.x * 256 + threadIdx.x;
  const float* src;
  int off;
  if (id < 16384) { src = wq; off = id; }
  else if (id < 32768) { src = wk; off = id - 16384; }
  else if (id < 49152) { src = wv; off = id - 32768; }
  else if (id < 98304) { src = apo; off = id - 49152; }
  else if (id < 229376) { src = fin; off = id - 98304; }
  else if (id < 425984) { src = fpo; off = id - 229376; }
  else return;
  dst[id] = f2bu(src[off]);
}

// load 16-elem window rv[j] = row[cb-4+j], zero-padded outside [0,64)
__device__ __forceinline__ void loadrow_bf(const ushort_t* __restrict__ rowp,
                                           int cb, float* rv) {
#pragma unroll
  for (int b = 0; b < 4; b++) {
    int co = cb - 4 + b * 4;
    if ((unsigned)co <= 60u) {
      us4 t = *(const us4*)(rowp + co);
      rv[b * 4 + 0] = bf2f(t.x); rv[b * 4 + 1] = bf2f(t.y);
      rv[b * 4 + 2] = bf2f(t.z); rv[b * 4 + 3] = bf2f(t.w);
    } else {
      rv[b * 4 + 0] = 0.f; rv[b * 4 + 1] = 0.f;
      rv[b * 4 + 2] = 0.f; rv[b * 4 + 3] = 0.f;
    }
  }
}

// ------- conv1x1 as bf16 MFMA GEMM: Out[cout][HW] = W[cout][cin] @ In[cin][HW] -------
// Transposed LDS tile [n][k] (stride ST2). Staging v2 (R18): one coalesced us4
// global load per thread (512B/wave-instr) + 4 scalar ds_write_u16 (2-way bank = free),
// replacing 4 scalar 2B global loads (128B/wave-instr). B-frag = one ds_read_b128.
template <typename Tin, typename Tout>
__global__ __launch_bounds__(256) void conv1x1_m(const Tin* __restrict__ in,
                                                 const ushort_t* __restrict__ wtb,
                                                 const float* __restrict__ resid,
                                                 Tout* __restrict__ out,
                                                 int cin, int cout, int wstride,
                                                 int accum) {
  constexpr int ST2 = 136;
  __shared__ ushort_t bsh[64 * ST2];
  int tid = threadIdx.x;
  int lane = tid & 63;
  int wid = tid >> 6;
  int lrow = lane & 15;
  int lk = lane >> 4;
  int blk = blockIdx.x;
  int nb = blk & 63;
  int rest = blk >> 6;
  int mb = cout >> 6;
  int m = rest % mb;
  int bi = rest / mb;
  int n0 = nb << 6;
  int o0 = (m << 6) + wid * 16;

  f32x4 acc[4] = {{0.f, 0.f, 0.f, 0.f}, {0.f, 0.f, 0.f, 0.f},
                  {0.f, 0.f, 0.f, 0.f}, {0.f, 0.f, 0.f, 0.f}};

  int nq = tid & 15;   // n-quad: n = n0 + nq*4 .. +3
  int kg = tid >> 4;   // k-group: 16 groups, each covers 8 k per chunk
  for (int kc = 0; kc < cin; kc += 128) {
    // ---- stage In[kc..kc+127][n0..n0+63] -> transposed bf16 LDS [n][k] ----
#pragma unroll
    for (int p = 0; p < 8; p++) {
      int k = p * 16 + kg;
      if constexpr (sizeof(Tin) == 2) {
        us4 v = *(const us4*)(in + ((size_t)bi * cin + kc + k) * HW_ + n0 + nq * 4);
        bsh[(nq * 4 + 0) * ST2 + k] = v.x;
        bsh[(nq * 4 + 1) * ST2 + k] = v.y;
        bsh[(nq * 4 + 2) * ST2 + k] = v.z;
        bsh[(nq * 4 + 3) * ST2 + k] = v.w;
      } else {
        float4 v = *(const float4*)((const float*)in +
                                    ((size_t)bi * cin + kc + k) * HW_ + n0 + nq * 4);
        bsh[(nq * 4 + 0) * ST2 + k] = f2bu(v.x);
        bsh[(nq * 4 + 1) * ST2 + k] = f2bu(v.y);
        bsh[(nq * 4 + 2) * ST2 + k] = f2bu(v.z);
        bsh[(nq * 4 + 3) * ST2 + k] = f2bu(v.w);
      }
    }
    __syncthreads();
#pragma unroll
    for (int ks = 0; ks < 4; ks++) {
      const ushort_t* wr = wtb + (size_t)(o0 + lrow) * wstride + kc + ks * 32 + lk * 8;
      us4 wlo = *(const us4*)wr;
      us4 whi = *(const us4*)(wr + 4);
      bf16x8 af;
      af[0] = (short)wlo.x; af[1] = (short)wlo.y;
      af[2] = (short)wlo.z; af[3] = (short)wlo.w;
      af[4] = (short)whi.x; af[5] = (short)whi.y;
      af[6] = (short)whi.z; af[7] = (short)whi.w;
#pragma unroll
      for (int s = 0; s < 4; s++) {
        bf16x8 bf_ = *(const bf16x8*)&bsh[(s * 16 + lrow) * ST2 + ks * 32 + lk * 8];
        acc[s] = __builtin_amdgcn_mfma_f32_16x16x32_bf16(af, bf_, acc[s], 0, 0, 0);
      }
    }
    __syncthreads();
  }

  const float* rp = resid ? resid + (size_t)bi * cout * HW_ : nullptr;
  Tout* op = out + (size_t)bi * cout * HW_;
#pragma unroll
  for (int s = 0; s < 4; s++) {
#pragma unroll
    for (int r = 0; r < 4; r++) {
      int o = o0 + lk * 4 + r;
      int n = n0 + s * 16 + lrow;
      size_t off = (size_t)o * HW_ + n;
      float v = acc[s][r];
      if (rp) v += rp[off];
      if (accum) v += toF(op[off]);
      storeF(&op[off], v);
    }
  }
}

// ------- depthwise conv (bf16 in/out), fused L2 sum-of-squares for q,k -------
template <int K>
__global__ __launch_bounds__(256) void dwconv_d(const ushort_t* __restrict__ qkv0,
                                                const float* __restrict__ wq_,
                                                const float* __restrict__ wk_,
                                                const float* __restrict__ wv_,
                                                ushort_t* __restrict__ qd,
                                                ushort_t* __restrict__ kd,
                                                ushort_t* __restrict__ vd,
                                                float* __restrict__ sumsq_s) {
  constexpr int P = K / 2;
  __shared__ float wsh[K * K];
  __shared__ float red[4];
  int sel = blockIdx.y;
  const float* wgt = (sel == 0) ? wq_ : (sel == 1) ? wk_ : wv_;
  ushort_t* outp = (sel == 0) ? qd : (sel == 1) ? kd : vd;
  int blk = blockIdx.x;  // B*C*2
  int half = blk & 1;
  int c = (blk >> 1) & (C_ - 1);
  int bi = blk >> 8;
  int tid = threadIdx.x;

  if (tid < K * K) wsh[tid] = wgt[(size_t)c * K * K + tid];
  __syncthreads();

  int r = tid >> 3;
  int cb = (tid & 7) << 3;
  int y = half * 32 + r;
  const ushort_t* plane = qkv0 + ((size_t)bi * 384 + sel * C_ + c) * HW_;

  float a[8];
#pragma unroll
  for (int o = 0; o < 8; o++) a[o] = 0.f;
#pragma unroll
  for (int dy = 0; dy < K; dy++) {
    int gy = y + dy - P;
    if ((unsigned)gy < 64u) {
      float rv[16];
      loadrow_bf(plane + gy * 64, cb, rv);
#pragma unroll
      for (int dx = 0; dx < K; dx++) {
        float wv = wsh[dy * K + dx];
#pragma unroll
        for (int o = 0; o < 8; o++) a[o] = fmaf(rv[o + dx + 4 - P], wv, a[o]);
      }
    }
  }
  ushort_t* ob = outp + (size_t)(bi * C_ + c) * HW_ + y * 64 + cb;
  us4 t0, t1;
  t0.x = f2bu(a[0]); t0.y = f2bu(a[1]); t0.z = f2bu(a[2]); t0.w = f2bu(a[3]);
  t1.x = f2bu(a[4]); t1.y = f2bu(a[5]); t1.z = f2bu(a[6]); t1.w = f2bu(a[7]);
  *(us4*)ob = t0;
  *(us4*)(ob + 4) = t1;

  float ssq = 0.f;
#pragma unroll
  for (int o = 0; o < 8; o++) ssq = fmaf(a[o], a[o], ssq);
#pragma unroll
  for (int off = 32; off >= 1; off >>= 1) ssq += __shfl_xor(ssq, off, 64);
  if ((tid & 63) == 0) red[tid >> 6] = ssq;
  __syncthreads();
  if (tid == 0 && sel < 2) {
    atomicAdd(&sumsq_s[sel * 1024 + bi * C_ + c], red[0] + red[1] + red[2] + red[3]);
  }
}

// ------- FFN depthwise conv + GEGLU gate, 2x8 patch/thread (R15-proven) -------
template <int K>
__global__ __launch_bounds__(256) void ffn_dwgate_p(const ushort_t* __restrict__ xin,
                                                    const float* __restrict__ w,
                                                    ushort_t* __restrict__ gated) {
  constexpr int P = K / 2;
  __shared__ float wsh[2 * K * K];
  int blk = blockIdx.x;  // B*512
  int i = blk & 511;
  int bi = blk >> 9;
  int tid = threadIdx.x;

  if (tid < 2 * K * K) {
    wsh[tid] = (tid < K * K) ? w[(size_t)i * K * K + tid]
                             : w[(size_t)(512 + i) * K * K + (tid - K * K)];
  }
  __syncthreads();

  int r2 = tid >> 3;          // 0..31
  int cb = (tid & 7) << 3;
  int y0 = r2 * 2;
  const ushort_t* gin = xin + (size_t)(bi * 1024 + i) * HW_;
  const ushort_t* min_ = gin + (size_t)512 * HW_;

  float ge[16];
  {
    float a0[8], a1[8];
#pragma unroll
    for (int o = 0; o < 8; o++) { a0[o] = 0.f; a1[o] = 0.f; }
#pragma unroll
    for (int rr = 0; rr <= K; rr++) {
      int gy = y0 - P + rr;
      if ((unsigned)gy < 64u) {
        float rv[16];
        loadrow_bf(gin + gy * 64, cb, rv);
        if (rr < K) {
          float wv;
#pragma unroll
          for (int dx = 0; dx < K; dx++) {
            wv = wsh[rr * K + dx];
#pragma unroll
            for (int o = 0; o < 8; o++) a0[o] = fmaf(rv[o + dx + 4 - P], wv, a0[o]);
          }
        }
        if (rr >= 1) {
          float wv;
#pragma unroll
          for (int dx = 0; dx < K; dx++) {
            wv = wsh[(rr - 1) * K + dx];
#pragma unroll
            for (int o = 0; o < 8; o++) a1[o] = fmaf(rv[o + dx + 4 - P], wv, a1[o]);
          }
        }
      }
    }
#pragma unroll
    for (int o = 0; o < 8; o++) { ge[o] = gelu_t(a0[o]); ge[8 + o] = gelu_t(a1[o]); }
  }

  float m0[8], m1[8];
#pragma unroll
  for (int o = 0; o < 8; o++) { m0[o] = 0.f; m1[o] = 0.f; }
#pragma unroll
  for (int rr = 0; rr <= K; rr++) {
    int gy = y0 - P + rr;
    if ((unsigned)gy < 64u) {
      float rv[16];
      loadrow_bf(min_ + gy * 64, cb, rv);
      if (rr < K) {
        float wv;
#pragma unroll
        for (int dx = 0; dx < K; dx++) {
          wv = wsh[K * K + rr * K + dx];
#pragma unroll
          for (int o = 0; o < 8; o++) m0[o] = fmaf(rv[o + dx + 4 - P], wv, m0[o]);
        }
      }
      if (rr >= 1) {
        float wv;
#pragma unroll
        for (int dx = 0; dx < K; dx++) {
          wv = wsh[K * K + (rr - 1) * K + dx];
#pragma unroll
          for (int o = 0; o < 8; o++) m1[o] = fmaf(rv[o + dx + 4 - P], wv, m1[o]);
        }
      }
    }
  }
  ushort_t* gp = gated + (size_t)(bi * 512 + i) * HW_ + y0 * 64 + cb;
#pragma unroll
  for (int v = 0; v < 2; v++) {
    us4 t;
    t.x = f2bu(ge[v * 4 + 0] * m0[v * 4 + 0]);
    t.y = f2bu(ge[v * 4 + 1] * m0[v * 4 + 1]);
    t.z = f2bu(ge[v * 4 + 2] * m0[v * 4 + 2]);
    t.w = f2bu(ge[v * 4 + 3] * m0[v * 4 + 3]);
    *(us4*)(gp + v * 4) = t;
  }
  gp += 64;
#pragma unroll
  for (int v = 0; v < 2; v++) {
    us4 t;
    t.x = f2bu(ge[8 + v * 4 + 0] * m1[v * 4 + 0]);
    t.y = f2bu(ge[8 + v * 4 + 1] * m1[v * 4 + 1]);
    t.z = f2bu(ge[8 + v * 4 + 2] * m1[v * 4 + 2]);
    t.w = f2bu(ge[8 + v * 4 + 3] * m1[v * 4 + 3]);
    *(us4*)(gp + v * 4) = t;
  }
}

// ---------------- attention: partial scores over 256-position chunks (bf16 in) ----------------
__global__ __launch_bounds__(256) void attn_score_part(const ushort_t* __restrict__ qd,
                                                       const ushort_t* __restrict__ kd,
                                                       float* __restrict__ part) {
  constexpr int ST = 258;
  __shared__ float qs[16 * ST];
  __shared__ float ks[16 * ST];
  int bh = blockIdx.x;   // 64
  int ch = blockIdx.y;   // 16 chunks of 256
  int bi = bh >> 3;
  int h = bh & 7;
  int tid = threadIdx.x;
  int c = tid >> 4;
  int d = tid & 15;

  const ushort_t* qrow = qd + (size_t)(bi * C_ + h * CH_) * HW_ + ch * 256;
  const ushort_t* krow = kd + (size_t)(bi * C_ + h * CH_) * HW_ + ch * 256;
#pragma unroll
  for (int it = 0; it < 4; it++) {
    int idx = tid + it * 256;
    int r = idx >> 6, q4 = idx & 63;
    us4 qv = *(const us4*)(qrow + (size_t)r * HW_ + q4 * 4);
    us4 kv = *(const us4*)(krow + (size_t)r * HW_ + q4 * 4);
    float* qdst = &qs[r * ST + q4 * 4];
    float* kdst = &ks[r * ST + q4 * 4];
    qdst[0] = bf2f(qv.x); qdst[1] = bf2f(qv.y); qdst[2] = bf2f(qv.z); qdst[3] = bf2f(qv.w);
    kdst[0] = bf2f(kv.x); kdst[1] = bf2f(kv.y); kdst[2] = bf2f(kv.z); kdst[3] = bf2f(kv.w);
  }
  __syncthreads();

  const float* qp = &qs[c * ST];
  const float* kp = &ks[d * ST];
  float acc = 0.f;
#pragma unroll 8
  for (int j = 0; j < 256; j++) acc = fmaf(qp[j], kp[j], acc);
  part[((size_t)bh * 16 + ch) * 256 + tid] = acc;
}

// ------- attention: fused softmax + PV; writes merged osb_all [bi][384][HW] -------
__global__ __launch_bounds__(256) void attn_pv_sm(const ushort_t* __restrict__ vd,
                                                  const float* __restrict__ part,
                                                  const float* __restrict__ sumsq_s,
                                                  const float* __restrict__ temp,
                                                  ushort_t* __restrict__ osb_all,
                                                  int coff) {
  __shared__ float as[16][17];
  int bh = blockIdx.x;  // 64
  int ch = blockIdx.y;  // 16
  int bi = bh >> 3;
  int h = bh & 7;
  int tid = threadIdx.x;

  {
    int c = tid >> 4;
    int d = tid & 15;
    float s = 0.f;
    const float* pp = part + (size_t)bh * 16 * 256 + tid;
#pragma unroll
    for (int c2 = 0; c2 < 16; c2++) s += pp[c2 * 256];
    float sq = sumsq_s[bi * C_ + h * CH_ + c];
    float sk = sumsq_s[1024 + bi * C_ + h * CH_ + d];
    float invq = 1.f / fmaxf(sqrtf(sq), 1e-12f);
    float invk = 1.f / fmaxf(sqrtf(sk), 1e-12f);
    float S = s * invq * invk * temp[h];
    float mx = S;
#pragma unroll
    for (int o = 8; o >= 1; o >>= 1) mx = fmaxf(mx, __shfl_xor(mx, o, 16));
    float e = expf(S - mx);
    float sm = e;
#pragma unroll
    for (int o = 8; o >= 1; o >>= 1) sm += __shfl_xor(sm, o, 16);
    as[c][d] = e / sm;
  }
  __syncthreads();

  int n = ch * 256 + tid;
  const ushort_t* vrow = vd + (size_t)(bi * C_ + h * CH_) * HW_ + n;
  float o_[16];
#pragma unroll
  for (int cc = 0; cc < 16; cc++) o_[cc] = 0.f;
#pragma unroll
  for (int dd = 0; dd < 16; dd++) {
    float vv = bf2f(vrow[(size_t)dd * HW_]);
#pragma unroll
    for (int cc = 0; cc < 16; cc++) o_[cc] = fmaf(as[cc][dd], vv, o_[cc]);
  }
  ushort_t* ob = osb_all + ((size_t)bi * 384 + coff + h * CH_) * HW_ + n;
#pragma unroll
  for (int cc = 0; cc < 16; cc++) ob[(size_t)cc * HW_] = f2bu(o_[cc]);
}

extern "C" void kernel_launch(void* const* d_in, const int* in_sizes, int n_in,
                              void* d_out, int out_size, void* d_ws, size_t ws_size,
                              hipStream_t stream) {
  const float* x = (const float*)d_in[0];
  const float* ln1_w = (const float*)d_in[1];
  const float* ln1_b = (const float*)d_in[2];
  const float* temp = (const float*)d_in[3];
  const float* wq = (const float*)d_in[4];
  const float* wk = (const float*)d_in[5];
  const float* wv = (const float*)d_in[6];
  const float* dw[9];
  for (int i = 0; i < 9; i++) dw[i] = (const float*)d_in[7 + i];
  const float* attn_po = (const float*)d_in[16];
  const float* ln2_w = (const float*)d_in[17];
  const float* ln2_b = (const float*)d_in[18];
  const float* ffn_in = (const float*)d_in[19];
  const float* ffn_dw[3] = {(const float*)d_in[20], (const float*)d_in[21],
                            (const float*)d_in[22]};
  const float* ffn_po = (const float*)d_in[23];
  float* out = (float*)d_out;

  // ---- workspace layout (bf16 intermediates), lifetime-aliased ----
  const size_t MB = (size_t)1 << 20;
  char* wsb = (char*)d_ws;
  ushort_t* xnb = (ushort_t*)(wsb + 0 * MB);
  float* part = (float*)(wsb + 0 * MB);  // 1MB; xnb dead when used
  ushort_t* qkv0 = (ushort_t*)(wsb + 16 * MB);     // 24MB
  ushort_t* qdb = (ushort_t*)(wsb + 40 * MB);      // 8MB
  ushort_t* kdb = (ushort_t*)(wsb + 48 * MB);
  ushort_t* vdb = (ushort_t*)(wsb + 56 * MB);
  ushort_t* osb_all = (ushort_t*)(wsb + 64 * MB);  // 24MB
  float* x2 = (float*)(wsb + 112 * MB);            // 16MB
  float* sumsq = (float*)(wsb + 128 * MB);                   // 24 KiB
  ushort_t* wbuf = (ushort_t*)(wsb + 128 * MB + 32 * 1024);  // 832 KiB
  ushort_t* xin = (ushort_t*)(wsb + 16 * MB);      // 64MB (attn buffers dead)
  ushort_t* gated = (ushort_t*)(wsb + 80 * MB);    // 32MB

  const ushort_t* wb_qkv = wbuf;            // [384][128]
  const ushort_t* wb_apo = wbuf + 49152;    // [128][384]
  const ushort_t* wb_fin = wbuf + 98304;    // [1024][128]
  const ushort_t* wb_fpo = wbuf + 229376;   // [128][1536]

  const int ln_grid = (B_ * HW_) / 256;                  // 128
  const int g_qkv = B_ * (384 / 64) * 64;                // 3072
  const int g128 = B_ * (C_ / 64) * 64;                  // 1024
  const int g1024 = B_ * (1024 / 64) * 64;               // 8192
  const dim3 dwt_grid(B_ * C_ * 2, 3);                   // 2048 x 3
  const int ffg_grid = B_ * 512;                         // 4096
  const dim3 att_grid(B_ * HEADS_, 16);                  // 64 x 16

  // ---- prep ----
  hipMemsetAsync(sumsq, 0, 3 * 2048 * sizeof(float), stream);
  cvt_w<<<1664, 256, 0, stream>>>(wq, wk, wv, attn_po, ffn_in, ffn_po, wbuf);

  // ---- attention branch ----
  ln_ch<<<ln_grid, 256, 0, stream>>>(x, ln1_w, ln1_b, xnb);
  conv1x1_m<ushort_t, ushort_t><<<g_qkv, 256, 0, stream>>>(
      xnb, wb_qkv, nullptr, qkv0, C_, 384, C_, 0);

  for (int s = 0; s < 3; s++) {
    float* sumsq_s = sumsq + s * 2048;
    if (s == 0)
      dwconv_d<3><<<dwt_grid, 256, 0, stream>>>(qkv0, dw[0], dw[1], dw[2],
                                                qdb, kdb, vdb, sumsq_s);
    else if (s == 1)
      dwconv_d<5><<<dwt_grid, 256, 0, stream>>>(qkv0, dw[3], dw[4], dw[5],
                                                qdb, kdb, vdb, sumsq_s);
    else
      dwconv_d<7><<<dwt_grid, 256, 0, stream>>>(qkv0, dw[6], dw[7], dw[8],
                                                qdb, kdb, vdb, sumsq_s);
    attn_score_part<<<att_grid, 256, 0, stream>>>(qdb, kdb, part);
    attn_pv_sm<<<att_grid, 256, 0, stream>>>(vdb, part, sumsq_s, temp, osb_all,
                                             s * C_);
  }
  // single merged attn_po GEMM: x2 = x + attn_po @ osb_all (cin=384)
  conv1x1_m<ushort_t, float><<<g128, 256, 0, stream>>>(
      osb_all, wb_apo, x, x2, 384, C_, 384, 0);

  // ---- FFN branch ----
  ln_ch<<<ln_grid, 256, 0, stream>>>(x2, ln2_w, ln2_b, xnb);
  conv1x1_m<ushort_t, ushort_t><<<g1024, 256, 0, stream>>>(
      xnb, wb_fin, nullptr, xin, C_, 1024, C_, 0);

  for (int s = 0; s < 3; s++) {
    if (s == 0)
      ffn_dwgate_p<3><<<ffg_grid, 256, 0, stream>>>(xin, ffn_dw[0], gated);
    else if (s == 1)
      ffn_dwgate_p<5><<<ffg_grid, 256, 0, stream>>>(xin, ffn_dw[1], gated);
    else
      ffn_dwgate_p<7><<<ffg_grid, 256, 0, stream>>>(xin, ffn_dw[2], gated);
    conv1x1_m<ushort_t, float><<<g128, 256, 0, stream>>>(
        gated, wb_fpo + s * 512, (s == 0) ? x2 : nullptr, out, 512, C_, 3 * HID_,
        s == 0 ? 0 : 1);
  }
  (void)in_sizes; (void)n_in; (void)out_size; (void)ws_size;
}

// Round 19
// 436.615 us; speedup vs baseline: 1.0826x; 1.0826x over previous
//
#include <hip/hip_runtime.h>
#include <hip/hip_bf16.h>
#include <math.h>

#define B_ 8
#define C_ 128
#define H_ 64
#define W_ 64
#define HW_ 4096
#define HEADS_ 8
#define CH_ 16
#define HID_ 512

typedef unsigned short ushort_t;
struct __attribute__((aligned(8))) us4 { ushort_t x, y, z, w; };

typedef __attribute__((ext_vector_type(8))) short bf16x8;
typedef __attribute__((ext_vector_type(4))) float f32x4;

__device__ __forceinline__ float bf2f(ushort_t u) {
  return __uint_as_float(((unsigned int)u) << 16);
}
__device__ __forceinline__ ushort_t f2bu(float f) {
  __hip_bfloat16 h = __float2bfloat16(f);
  return *reinterpret_cast<ushort_t*>(&h);
}
__device__ __forceinline__ float toF(float v) { return v; }
__device__ __forceinline__ float toF(ushort_t v) { return bf2f(v); }
__device__ __forceinline__ void storeF(float* p, float v) { *p = v; }
__device__ __forceinline__ void storeF(ushort_t* p, float v) { *p = f2bu(v); }

// tanh-GELU: max dev from exact erf-GELU ~1e-3, straight-line
__device__ __forceinline__ float gelu_t(float x) {
  float z = 0.7978845608f * fmaf(0.044715f * x, x * x, x);
  float e = __expf(2.f * z);
  float th = 1.f - 2.f / (e + 1.f);
  return 0.5f * x * (1.f + th);
}

// ---------------- LayerNorm over channel dim (bf16 out) ----------------
__global__ __launch_bounds__(256) void ln_ch(const float* __restrict__ x,
                                             const float* __restrict__ w,
                                             const float* __restrict__ b,
                                             ushort_t* __restrict__ out) {
  int p = blockIdx.x * 256 + threadIdx.x;  // over B*HW
  int bi = p >> 12;
  int pos = p & (HW_ - 1);
  const float* xb = x + (size_t)bi * C_ * HW_ + pos;
  float s = 0.f, ss = 0.f;
  for (int c = 0; c < C_; c++) {
    float v = xb[(size_t)c * HW_];
    s += v;
    ss = fmaf(v, v, ss);
  }
  float mu = s * (1.f / C_);
  float var = ss * (1.f / C_) - mu * mu;
  float inv = rsqrtf(var + 1e-5f);
  ushort_t* ob = out + (size_t)bi * C_ * HW_ + pos;
  for (int c = 0; c < C_; c++) {
    ob[(size_t)c * HW_] = f2bu((xb[(size_t)c * HW_] - mu) * inv * w[c] + b[c]);
  }
}

// ---------------- weight prep: fp32 -> bf16, all six matrices ----------------
__global__ __launch_bounds__(256) void cvt_w(const float* __restrict__ wq,
                                             const float* __restrict__ wk,
                                             const float* __restrict__ wv,
                                             const float* __restrict__ apo,
                                             const float* __restrict__ fin,
                                             const float* __restrict__ fpo,
                                             ushort_t* __restrict__ dst) {
  int id = blockIdx.x * 256 + threadIdx.x;
  const float* src;
  int off;
  if (id < 16384) { src = wq; off = id; }
  else if (id < 32768) { src = wk; off = id - 16384; }
  else if (id < 49152) { src = wv; off = id - 32768; }
  else if (id < 98304) { src = apo; off = id - 49152; }
  else if (id < 229376) { src = fin; off = id - 98304; }
  else if (id < 425984) { src = fpo; off = id - 229376; }
  else return;
  dst[id] = f2bu(src[off]);
}

// load 16-elem window rv[j] = row[cb-4+j], zero-padded outside [0,64)
__device__ __forceinline__ void loadrow_bf(const ushort_t* __restrict__ rowp,
                                           int cb, float* rv) {
#pragma unroll
  for (int b = 0; b < 4; b++) {
    int co = cb - 4 + b * 4;
    if ((unsigned)co <= 60u) {
      us4 t = *(const us4*)(rowp + co);
      rv[b * 4 + 0] = bf2f(t.x); rv[b * 4 + 1] = bf2f(t.y);
      rv[b * 4 + 2] = bf2f(t.z); rv[b * 4 + 3] = bf2f(t.w);
    } else {
      rv[b * 4 + 0] = 0.f; rv[b * 4 + 1] = 0.f;
      rv[b * 4 + 2] = 0.f; rv[b * 4 + 3] = 0.f;
    }
  }
}

// ------- conv1x1 as bf16 MFMA GEMM: Out[cout][HW] = W[cout][cin] @ In[cin][HW] -------
// Transposed LDS tile [n][k]; staging = per-thread scalar global loads packed into
// one ds_write_b64 (R14/R16-proven; R18's us4-load + scalar ds_writes regressed).
template <typename Tin, typename Tout>
__global__ __launch_bounds__(256) void conv1x1_m(const Tin* __restrict__ in,
                                                 const ushort_t* __restrict__ wtb,
                                                 const float* __restrict__ resid,
                                                 Tout* __restrict__ out,
                                                 int cin, int cout, int wstride,
                                                 int accum) {
  constexpr int ST2 = 136;
  __shared__ ushort_t bsh[64 * ST2];
  int tid = threadIdx.x;
  int lane = tid & 63;
  int wid = tid >> 6;
  int lrow = lane & 15;
  int lk = lane >> 4;
  int blk = blockIdx.x;
  int nb = blk & 63;
  int rest = blk >> 6;
  int mb = cout >> 6;
  int m = rest % mb;
  int bi = rest / mb;
  int n0 = nb << 6;
  int o0 = (m << 6) + wid * 16;

  f32x4 acc[4] = {{0.f, 0.f, 0.f, 0.f}, {0.f, 0.f, 0.f, 0.f},
                  {0.f, 0.f, 0.f, 0.f}, {0.f, 0.f, 0.f, 0.f}};

  int nn = tid & 63;   // staging: n within tile
  int wk4 = tid >> 6;  // staging: k-quad selector
  for (int kc = 0; kc < cin; kc += 128) {
#pragma unroll
    for (int p = 0; p < 8; p++) {
      int kb = p * 16 + wk4 * 4;
      ushort_t u[4];
#pragma unroll
      for (int j = 0; j < 4; j++) {
        const Tin* src = in + ((size_t)bi * cin + kc + kb + j) * HW_ + n0 + nn;
        if constexpr (sizeof(Tin) == 4) {
          u[j] = f2bu(*(const float*)src);
        } else {
          u[j] = *(const ushort_t*)src;
        }
      }
      us4 w4;
      w4.x = u[0]; w4.y = u[1]; w4.z = u[2]; w4.w = u[3];
      *(us4*)&bsh[nn * ST2 + kb] = w4;
    }
    __syncthreads();
#pragma unroll
    for (int ks = 0; ks < 4; ks++) {
      const ushort_t* wr = wtb + (size_t)(o0 + lrow) * wstride + kc + ks * 32 + lk * 8;
      us4 wlo = *(const us4*)wr;
      us4 whi = *(const us4*)(wr + 4);
      bf16x8 af;
      af[0] = (short)wlo.x; af[1] = (short)wlo.y;
      af[2] = (short)wlo.z; af[3] = (short)wlo.w;
      af[4] = (short)whi.x; af[5] = (short)whi.y;
      af[6] = (short)whi.z; af[7] = (short)whi.w;
#pragma unroll
      for (int s = 0; s < 4; s++) {
        bf16x8 bf_ = *(const bf16x8*)&bsh[(s * 16 + lrow) * ST2 + ks * 32 + lk * 8];
        acc[s] = __builtin_amdgcn_mfma_f32_16x16x32_bf16(af, bf_, acc[s], 0, 0, 0);
      }
    }
    __syncthreads();
  }

  const float* rp = resid ? resid + (size_t)bi * cout * HW_ : nullptr;
  Tout* op = out + (size_t)bi * cout * HW_;
#pragma unroll
  for (int s = 0; s < 4; s++) {
#pragma unroll
    for (int r = 0; r < 4; r++) {
      int o = o0 + lk * 4 + r;
      int n = n0 + s * 16 + lrow;
      size_t off = (size_t)o * HW_ + n;
      float v = acc[s][r];
      if (rp) v += rp[off];
      if (accum) v += toF(op[off]);
      storeF(&op[off], v);
    }
  }
}

// ------- depthwise conv (bf16 in/out), fused L2 sum-of-squares for q,k -------
template <int K>
__global__ __launch_bounds__(256) void dwconv_d(const ushort_t* __restrict__ qkv0,
                                                const float* __restrict__ wq_,
                                                const float* __restrict__ wk_,
                                                const float* __restrict__ wv_,
                                                ushort_t* __restrict__ qd,
                                                ushort_t* __restrict__ kd,
                                                ushort_t* __restrict__ vd,
                                                float* __restrict__ sumsq_s) {
  constexpr int P = K / 2;
  __shared__ float wsh[K * K];
  __shared__ float red[4];
  int sel = blockIdx.y;
  const float* wgt = (sel == 0) ? wq_ : (sel == 1) ? wk_ : wv_;
  ushort_t* outp = (sel == 0) ? qd : (sel == 1) ? kd : vd;
  int blk = blockIdx.x;  // B*C*2
  int half = blk & 1;
  int c = (blk >> 1) & (C_ - 1);
  int bi = blk >> 8;
  int tid = threadIdx.x;

  if (tid < K * K) wsh[tid] = wgt[(size_t)c * K * K + tid];
  __syncthreads();

  int r = tid >> 3;
  int cb = (tid & 7) << 3;
  int y = half * 32 + r;
  const ushort_t* plane = qkv0 + ((size_t)bi * 384 + sel * C_ + c) * HW_;

  float a[8];
#pragma unroll
  for (int o = 0; o < 8; o++) a[o] = 0.f;
#pragma unroll
  for (int dy = 0; dy < K; dy++) {
    int gy = y + dy - P;
    if ((unsigned)gy < 64u) {
      float rv[16];
      loadrow_bf(plane + gy * 64, cb, rv);
#pragma unroll
      for (int dx = 0; dx < K; dx++) {
        float wv = wsh[dy * K + dx];
#pragma unroll
        for (int o = 0; o < 8; o++) a[o] = fmaf(rv[o + dx + 4 - P], wv, a[o]);
      }
    }
  }
  ushort_t* ob = outp + (size_t)(bi * C_ + c) * HW_ + y * 64 + cb;
  us4 t0, t1;
  t0.x = f2bu(a[0]); t0.y = f2bu(a[1]); t0.z = f2bu(a[2]); t0.w = f2bu(a[3]);
  t1.x = f2bu(a[4]); t1.y = f2bu(a[5]); t1.z = f2bu(a[6]); t1.w = f2bu(a[7]);
  *(us4*)ob = t0;
  *(us4*)(ob + 4) = t1;

  float ssq = 0.f;
#pragma unroll
  for (int o = 0; o < 8; o++) ssq = fmaf(a[o], a[o], ssq);
#pragma unroll
  for (int off = 32; off >= 1; off >>= 1) ssq += __shfl_xor(ssq, off, 64);
  if ((tid & 63) == 0) red[tid >> 6] = ssq;
  __syncthreads();
  if (tid == 0 && sel < 2) {
    atomicAdd(&sumsq_s[sel * 1024 + bi * C_ + c], red[0] + red[1] + red[2] + red[3]);
  }
}

// ------- FFN depthwise conv + GEGLU gate, 2x8 patch/thread (R15-proven) -------
template <int K>
__global__ __launch_bounds__(256) void ffn_dwgate_p(const ushort_t* __restrict__ xin,
                                                    const float* __restrict__ w,
                                                    ushort_t* __restrict__ gated) {
  constexpr int P = K / 2;
  __shared__ float wsh[2 * K * K];
  int blk = blockIdx.x;  // B*512
  int i = blk & 511;
  int bi = blk >> 9;
  int tid = threadIdx.x;

  if (tid < 2 * K * K) {
    wsh[tid] = (tid < K * K) ? w[(size_t)i * K * K + tid]
                             : w[(size_t)(512 + i) * K * K + (tid - K * K)];
  }
  __syncthreads();

  int r2 = tid >> 3;          // 0..31
  int cb = (tid & 7) << 3;
  int y0 = r2 * 2;
  const ushort_t* gin = xin + (size_t)(bi * 1024 + i) * HW_;
  const ushort_t* min_ = gin + (size_t)512 * HW_;

  float ge[16];
  {
    float a0[8], a1[8];
#pragma unroll
    for (int o = 0; o < 8; o++) { a0[o] = 0.f; a1[o] = 0.f; }
#pragma unroll
    for (int rr = 0; rr <= K; rr++) {
      int gy = y0 - P + rr;
      if ((unsigned)gy < 64u) {
        float rv[16];
        loadrow_bf(gin + gy * 64, cb, rv);
        if (rr < K) {
          float wv;
#pragma unroll
          for (int dx = 0; dx < K; dx++) {
            wv = wsh[rr * K + dx];
#pragma unroll
            for (int o = 0; o < 8; o++) a0[o] = fmaf(rv[o + dx + 4 - P], wv, a0[o]);
          }
        }
        if (rr >= 1) {
          float wv;
#pragma unroll
          for (int dx = 0; dx < K; dx++) {
            wv = wsh[(rr - 1) * K + dx];
#pragma unroll
            for (int o = 0; o < 8; o++) a1[o] = fmaf(rv[o + dx + 4 - P], wv, a1[o]);
          }
        }
      }
    }
#pragma unroll
    for (int o = 0; o < 8; o++) { ge[o] = gelu_t(a0[o]); ge[8 + o] = gelu_t(a1[o]); }
  }

  float m0[8], m1[8];
#pragma unroll
  for (int o = 0; o < 8; o++) { m0[o] = 0.f; m1[o] = 0.f; }
#pragma unroll
  for (int rr = 0; rr <= K; rr++) {
    int gy = y0 - P + rr;
    if ((unsigned)gy < 64u) {
      float rv[16];
      loadrow_bf(min_ + gy * 64, cb, rv);
      if (rr < K) {
        float wv;
#pragma unroll
        for (int dx = 0; dx < K; dx++) {
          wv = wsh[K * K + rr * K + dx];
#pragma unroll
          for (int o = 0; o < 8; o++) m0[o] = fmaf(rv[o + dx + 4 - P], wv, m0[o]);
        }
      }
      if (rr >= 1) {
        float wv;
#pragma unroll
        for (int dx = 0; dx < K; dx++) {
          wv = wsh[K * K + (rr - 1) * K + dx];
#pragma unroll
          for (int o = 0; o < 8; o++) m1[o] = fmaf(rv[o + dx + 4 - P], wv, m1[o]);
        }
      }
    }
  }
  ushort_t* gp = gated + (size_t)(bi * 512 + i) * HW_ + y0 * 64 + cb;
#pragma unroll
  for (int v = 0; v < 2; v++) {
    us4 t;
    t.x = f2bu(ge[v * 4 + 0] * m0[v * 4 + 0]);
    t.y = f2bu(ge[v * 4 + 1] * m0[v * 4 + 1]);
    t.z = f2bu(ge[v * 4 + 2] * m0[v * 4 + 2]);
    t.w = f2bu(ge[v * 4 + 3] * m0[v * 4 + 3]);
    *(us4*)(gp + v * 4) = t;
  }
  gp += 64;
#pragma unroll
  for (int v = 0; v < 2; v++) {
    us4 t;
    t.x = f2bu(ge[8 + v * 4 + 0] * m1[v * 4 + 0]);
    t.y = f2bu(ge[8 + v * 4 + 1] * m1[v * 4 + 1]);
    t.z = f2bu(ge[8 + v * 4 + 2] * m1[v * 4 + 2]);
    t.w = f2bu(ge[8 + v * 4 + 3] * m1[v * 4 + 3]);
    *(us4*)(gp + v * 4) = t;
  }
}

// ---------------- attention: partial scores over 256-position chunks (bf16 in) ----------------
__global__ __launch_bounds__(256) void attn_score_part(const ushort_t* __restrict__ qd,
                                                       const ushort_t* __restrict__ kd,
                                                       float* __restrict__ part) {
  constexpr int ST = 258;
  __shared__ float qs[16 * ST];
  __shared__ float ks[16 * ST];
  int bh = blockIdx.x;   // 64
  int ch = blockIdx.y;   // 16 chunks of 256
  int bi = bh >> 3;
  int h = bh & 7;
  int tid = threadIdx.x;
  int c = tid >> 4;
  int d = tid & 15;

  const ushort_t* qrow = qd + (size_t)(bi * C_ + h * CH_) * HW_ + ch * 256;
  const ushort_t* krow = kd + (size_t)(bi * C_ + h * CH_) * HW_ + ch * 256;
#pragma unroll
  for (int it = 0; it < 4; it++) {
    int idx = tid + it * 256;
    int r = idx >> 6, q4 = idx & 63;
    us4 qv = *(const us4*)(qrow + (size_t)r * HW_ + q4 * 4);
    us4 kv = *(const us4*)(krow + (size_t)r * HW_ + q4 * 4);
    float* qdst = &qs[r * ST + q4 * 4];
    float* kdst = &ks[r * ST + q4 * 4];
    qdst[0] = bf2f(qv.x); qdst[1] = bf2f(qv.y); qdst[2] = bf2f(qv.z); qdst[3] = bf2f(qv.w);
    kdst[0] = bf2f(kv.x); kdst[1] = bf2f(kv.y); kdst[2] = bf2f(kv.z); kdst[3] = bf2f(kv.w);
  }
  __syncthreads();

  const float* qp = &qs[c * ST];
  const float* kp = &ks[d * ST];
  float acc = 0.f;
#pragma unroll 8
  for (int j = 0; j < 256; j++) acc = fmaf(qp[j], kp[j], acc);
  part[((size_t)bh * 16 + ch) * 256 + tid] = acc;
}

// ------- attention: fused softmax + PV; writes merged osb_all [bi][384][HW] -------
__global__ __launch_bounds__(256) void attn_pv_sm(const ushort_t* __restrict__ vd,
                                                  const float* __restrict__ part,
                                                  const float* __restrict__ sumsq_s,
                                                  const float* __restrict__ temp,
                                                  ushort_t* __restrict__ osb_all,
                                                  int coff) {
  __shared__ float as[16][17];
  int bh = blockIdx.x;  // 64
  int ch = blockIdx.y;  // 16
  int bi = bh >> 3;
  int h = bh & 7;
  int tid = threadIdx.x;

  {
    int c = tid >> 4;
    int d = tid & 15;
    float s = 0.f;
    const float* pp = part + (size_t)bh * 16 * 256 + tid;
#pragma unroll
    for (int c2 = 0; c2 < 16; c2++) s += pp[c2 * 256];
    float sq = sumsq_s[bi * C_ + h * CH_ + c];
    float sk = sumsq_s[1024 + bi * C_ + h * CH_ + d];
    float invq = 1.f / fmaxf(sqrtf(sq), 1e-12f);
    float invk = 1.f / fmaxf(sqrtf(sk), 1e-12f);
    float S = s * invq * invk * temp[h];
    float mx = S;
#pragma unroll
    for (int o = 8; o >= 1; o >>= 1) mx = fmaxf(mx, __shfl_xor(mx, o, 16));
    float e = expf(S - mx);
    float sm = e;
#pragma unroll
    for (int o = 8; o >= 1; o >>= 1) sm += __shfl_xor(sm, o, 16);
    as[c][d] = e / sm;
  }
  __syncthreads();

  int n = ch * 256 + tid;
  const ushort_t* vrow = vd + (size_t)(bi * C_ + h * CH_) * HW_ + n;
  float o_[16];
#pragma unroll
  for (int cc = 0; cc < 16; cc++) o_[cc] = 0.f;
#pragma unroll
  for (int dd = 0; dd < 16; dd++) {
    float vv = bf2f(vrow[(size_t)dd * HW_]);
#pragma unroll
    for (int cc = 0; cc < 16; cc++) o_[cc] = fmaf(as[cc][dd], vv, o_[cc]);
  }
  ushort_t* ob = osb_all + ((size_t)bi * 384 + coff + h * CH_) * HW_ + n;
#pragma unroll
  for (int cc = 0; cc < 16; cc++) ob[(size_t)cc * HW_] = f2bu(o_[cc]);
}

extern "C" void kernel_launch(void* const* d_in, const int* in_sizes, int n_in,
                              void* d_out, int out_size, void* d_ws, size_t ws_size,
                              hipStream_t stream) {
  const float* x = (const float*)d_in[0];
  const float* ln1_w = (const float*)d_in[1];
  const float* ln1_b = (const float*)d_in[2];
  const float* temp = (const float*)d_in[3];
  const float* wq = (const float*)d_in[4];
  const float* wk = (const float*)d_in[5];
  const float* wv = (const float*)d_in[6];
  const float* dw[9];
  for (int i = 0; i < 9; i++) dw[i] = (const float*)d_in[7 + i];
  const float* attn_po = (const float*)d_in[16];
  const float* ln2_w = (const float*)d_in[17];
  const float* ln2_b = (const float*)d_in[18];
  const float* ffn_in = (const float*)d_in[19];
  const float* ffn_dw[3] = {(const float*)d_in[20], (const float*)d_in[21],
                            (const float*)d_in[22]};
  const float* ffn_po = (const float*)d_in[23];
  float* out = (float*)d_out;

  // ---- workspace layout (bf16 intermediates), lifetime-aliased ----
  const size_t MB = (size_t)1 << 20;
  char* wsb = (char*)d_ws;
  ushort_t* xnb = (ushort_t*)(wsb + 0 * MB);
  float* part = (float*)(wsb + 0 * MB);  // 1MB; xnb dead when used
  ushort_t* qkv0 = (ushort_t*)(wsb + 16 * MB);     // 24MB
  ushort_t* qdb = (ushort_t*)(wsb + 40 * MB);      // 8MB
  ushort_t* kdb = (ushort_t*)(wsb + 48 * MB);
  ushort_t* vdb = (ushort_t*)(wsb + 56 * MB);
  ushort_t* osb_all = (ushort_t*)(wsb + 64 * MB);  // 24MB
  float* x2 = (float*)(wsb + 112 * MB);            // 16MB
  float* sumsq = (float*)(wsb + 128 * MB);                   // 24 KiB
  ushort_t* wbuf = (ushort_t*)(wsb + 128 * MB + 32 * 1024);  // 832 KiB
  ushort_t* xin = (ushort_t*)(wsb + 16 * MB);      // 64MB (attn buffers dead)
  ushort_t* gated = (ushort_t*)(wsb + 80 * MB);    // 32MB

  const ushort_t* wb_qkv = wbuf;            // [384][128]
  const ushort_t* wb_apo = wbuf + 49152;    // [128][384]
  const ushort_t* wb_fin = wbuf + 98304;    // [1024][128]
  const ushort_t* wb_fpo = wbuf + 229376;   // [128][1536]

  const int ln_grid = (B_ * HW_) / 256;                  // 128
  const int g_qkv = B_ * (384 / 64) * 64;                // 3072
  const int g128 = B_ * (C_ / 64) * 64;                  // 1024
  const int g1024 = B_ * (1024 / 64) * 64;               // 8192
  const dim3 dwt_grid(B_ * C_ * 2, 3);                   // 2048 x 3
  const int ffg_grid = B_ * 512;                         // 4096
  const dim3 att_grid(B_ * HEADS_, 16);                  // 64 x 16

  // ---- prep ----
  hipMemsetAsync(sumsq, 0, 3 * 2048 * sizeof(float), stream);
  cvt_w<<<1664, 256, 0, stream>>>(wq, wk, wv, attn_po, ffn_in, ffn_po, wbuf);

  // ---- attention branch ----
  ln_ch<<<ln_grid, 256, 0, stream>>>(x, ln1_w, ln1_b, xnb);
  conv1x1_m<ushort_t, ushort_t><<<g_qkv, 256, 0, stream>>>(
      xnb, wb_qkv, nullptr, qkv0, C_, 384, C_, 0);

  for (int s = 0; s < 3; s++) {
    float* sumsq_s = sumsq + s * 2048;
    if (s == 0)
      dwconv_d<3><<<dwt_grid, 256, 0, stream>>>(qkv0, dw[0], dw[1], dw[2],
                                                qdb, kdb, vdb, sumsq_s);
    else if (s == 1)
      dwconv_d<5><<<dwt_grid, 256, 0, stream>>>(qkv0, dw[3], dw[4], dw[5],
                                                qdb, kdb, vdb, sumsq_s);
    else
      dwconv_d<7><<<dwt_grid, 256, 0, stream>>>(qkv0, dw[6], dw[7], dw[8],
                                                qdb, kdb, vdb, sumsq_s);
    attn_score_part<<<att_grid, 256, 0, stream>>>(qdb, kdb, part);
    attn_pv_sm<<<att_grid, 256, 0, stream>>>(vdb, part, sumsq_s, temp, osb_all,
                                             s * C_);
  }
  // single merged attn_po GEMM: x2 = x + attn_po @ osb_all (cin=384)
  conv1x1_m<ushort_t, float><<<g128, 256, 0, stream>>>(
      osb_all, wb_apo, x, x2, 384, C_, 384, 0);

  // ---- FFN branch ----
  ln_ch<<<ln_grid, 256, 0, stream>>>(x2, ln2_w, ln2_b, xnb);
  conv1x1_m<ushort_t, ushort_t><<<g1024, 256, 0, stream>>>(
      xnb, wb_fin, nullptr, xin, C_, 1024, C_, 0);

  for (int s = 0; s < 3; s++) {
    if (s == 0)
      ffn_dwgate_p<3><<<ffg_grid, 256, 0, stream>>>(xin, ffn_dw[0], gated);
    else if (s == 1)
      ffn_dwgate_p<5><<<ffg_grid, 256, 0, stream>>>(xin, ffn_dw[1], gated);
    else
      ffn_dwgate_p<7><<<ffg_grid, 256, 0, stream>>>(xin, ffn_dw[2], gated);
    conv1x1_m<ushort_t, float><<<g128, 256, 0, stream>>>(
        gated, wb_fpo + s * 512, (s == 0) ? x2 : nullptr, out, 512, C_, 3 * HID_,
        s == 0 ? 0 : 1);
  }
  (void)in_sizes; (void)n_in; (void)out_size; (void)ws_size;
}

// Round 20
// 427.720 us; speedup vs baseline: 1.1051x; 1.0208x over previous
//
#include <hip/hip_runtime.h>
#include <hip/hip_bf16.h>
#include <math.h>

#define B_ 8
#define C_ 128
#define H_ 64
#define W_ 64
#define HW_ 4096
#define HEADS_ 8
#define CH_ 16
#define HID_ 512

typedef unsigned short ushort_t;
struct __attribute__((aligned(8))) us4 { ushort_t x, y, z, w; };

typedef __attribute__((ext_vector_type(8))) short bf16x8;
typedef __attribute__((ext_vector_type(4))) float f32x4;

__device__ __forceinline__ float bf2f(ushort_t u) {
  return __uint_as_float(((unsigned int)u) << 16);
}
__device__ __forceinline__ ushort_t f2bu(float f) {
  __hip_bfloat16 h = __float2bfloat16(f);
  return *reinterpret_cast<ushort_t*>(&h);
}
__device__ __forceinline__ float toF(float v) { return v; }
__device__ __forceinline__ float toF(ushort_t v) { return bf2f(v); }
__device__ __forceinline__ void storeF(float* p, float v) { *p = v; }
__device__ __forceinline__ void storeF(ushort_t* p, float v) { *p = f2bu(v); }

// tanh-GELU: max dev from exact erf-GELU ~1e-3, straight-line
__device__ __forceinline__ float gelu_t(float x) {
  float z = 0.7978845608f * fmaf(0.044715f * x, x * x, x);
  float e = __expf(2.f * z);
  float th = 1.f - 2.f / (e + 1.f);
  return 0.5f * x * (1.f + th);
}

// ------- LayerNorm over channel dim (bf16 out), v2: 64 pos/block x 4 ch-groups -------
// R19 post-mortem: v1 used grid=128 on 256 CUs (half idle). v2: grid=512, LDS reduce.
__global__ __launch_bounds__(256) void ln_ch(const float* __restrict__ x,
                                             const float* __restrict__ w,
                                             const float* __restrict__ b,
                                             ushort_t* __restrict__ out) {
  __shared__ float rs[4][64];
  __shared__ float rss[4][64];
  int tid = threadIdx.x;
  int pl = tid & 63;       // position within block
  int cg = tid >> 6;       // channel group 0..3 (32 channels each)
  int p = blockIdx.x * 64 + pl;  // over B*HW
  int bi = p >> 12;
  int pos = p & (HW_ - 1);
  const float* xb = x + (size_t)bi * C_ * HW_ + pos;
  float s = 0.f, ss = 0.f;
#pragma unroll 8
  for (int c = 0; c < 32; c++) {
    float v = xb[(size_t)(cg * 32 + c) * HW_];
    s += v;
    ss = fmaf(v, v, ss);
  }
  rs[cg][pl] = s;
  rss[cg][pl] = ss;
  __syncthreads();
  float ts = rs[0][pl] + rs[1][pl] + rs[2][pl] + rs[3][pl];
  float tss = rss[0][pl] + rss[1][pl] + rss[2][pl] + rss[3][pl];
  float mu = ts * (1.f / C_);
  float var = tss * (1.f / C_) - mu * mu;
  float inv = rsqrtf(var + 1e-5f);
  ushort_t* ob = out + (size_t)bi * C_ * HW_ + pos;
#pragma unroll 8
  for (int c = 0; c < 32; c++) {
    int ch = cg * 32 + c;
    ob[(size_t)ch * HW_] = f2bu((xb[(size_t)ch * HW_] - mu) * inv * w[ch] + b[ch]);
  }
}

// ---------------- weight prep: fp32 -> bf16, all six matrices ----------------
__global__ __launch_bounds__(256) void cvt_w(const float* __restrict__ wq,
                                             const float* __restrict__ wk,
                                             const float* __restrict__ wv,
                                             const float* __restrict__ apo,
                                             const float* __restrict__ fin,
                                             const float* __restrict__ fpo,
                                             ushort_t* __restrict__ dst) {
  int id = blockIdx.x * 256 + threadIdx.x;
  const float* src;
  int off;
  if (id < 16384) { src = wq; off = id; }
  else if (id < 32768) { src = wk; off = id - 16384; }
  else if (id < 49152) { src = wv; off = id - 32768; }
  else if (id < 98304) { src = apo; off = id - 49152; }
  else if (id < 229376) { src = fin; off = id - 98304; }
  else if (id < 425984) { src = fpo; off = id - 229376; }
  else return;
  dst[id] = f2bu(src[off]);
}

// load 16-elem window rv[j] = row[cb-4+j], zero-padded outside [0,64)
__device__ __forceinline__ void loadrow_bf(const ushort_t* __restrict__ rowp,
                                           int cb, float* rv) {
#pragma unroll
  for (int b = 0; b < 4; b++) {
    int co = cb - 4 + b * 4;
    if ((unsigned)co <= 60u) {
      us4 t = *(const us4*)(rowp + co);
      rv[b * 4 + 0] = bf2f(t.x); rv[b * 4 + 1] = bf2f(t.y);
      rv[b * 4 + 2] = bf2f(t.z); rv[b * 4 + 3] = bf2f(t.w);
    } else {
      rv[b * 4 + 0] = 0.f; rv[b * 4 + 1] = 0.f;
      rv[b * 4 + 2] = 0.f; rv[b * 4 + 3] = 0.f;
    }
  }
}

// ------- conv1x1 as bf16 MFMA GEMM: Out[cout][HW] = W[cout][cin] @ In[cin][HW] -------
// Transposed LDS tile [n][k]; staging = per-thread scalar global loads packed into
// one ds_write_b64 (R14/R16-proven).
template <typename Tin, typename Tout>
__global__ __launch_bounds__(256) void conv1x1_m(const Tin* __restrict__ in,
                                                 const ushort_t* __restrict__ wtb,
                                                 const float* __restrict__ resid,
                                                 Tout* __restrict__ out,
                                                 int cin, int cout, int wstride,
                                                 int accum) {
  constexpr int ST2 = 136;
  __shared__ ushort_t bsh[64 * ST2];
  int tid = threadIdx.x;
  int lane = tid & 63;
  int wid = tid >> 6;
  int lrow = lane & 15;
  int lk = lane >> 4;
  int blk = blockIdx.x;
  int nb = blk & 63;
  int rest = blk >> 6;
  int mb = cout >> 6;
  int m = rest % mb;
  int bi = rest / mb;
  int n0 = nb << 6;
  int o0 = (m << 6) + wid * 16;

  f32x4 acc[4] = {{0.f, 0.f, 0.f, 0.f}, {0.f, 0.f, 0.f, 0.f},
                  {0.f, 0.f, 0.f, 0.f}, {0.f, 0.f, 0.f, 0.f}};

  int nn = tid & 63;   // staging: n within tile
  int wk4 = tid >> 6;  // staging: k-quad selector
  for (int kc = 0; kc < cin; kc += 128) {
#pragma unroll
    for (int p = 0; p < 8; p++) {
      int kb = p * 16 + wk4 * 4;
      ushort_t u[4];
#pragma unroll
      for (int j = 0; j < 4; j++) {
        const Tin* src = in + ((size_t)bi * cin + kc + kb + j) * HW_ + n0 + nn;
        if constexpr (sizeof(Tin) == 4) {
          u[j] = f2bu(*(const float*)src);
        } else {
          u[j] = *(const ushort_t*)src;
        }
      }
      us4 w4;
      w4.x = u[0]; w4.y = u[1]; w4.z = u[2]; w4.w = u[3];
      *(us4*)&bsh[nn * ST2 + kb] = w4;
    }
    __syncthreads();
#pragma unroll
    for (int ks = 0; ks < 4; ks++) {
      const ushort_t* wr = wtb + (size_t)(o0 + lrow) * wstride + kc + ks * 32 + lk * 8;
      us4 wlo = *(const us4*)wr;
      us4 whi = *(const us4*)(wr + 4);
      bf16x8 af;
      af[0] = (short)wlo.x; af[1] = (short)wlo.y;
      af[2] = (short)wlo.z; af[3] = (short)wlo.w;
      af[4] = (short)whi.x; af[5] = (short)whi.y;
      af[6] = (short)whi.z; af[7] = (short)whi.w;
#pragma unroll
      for (int s = 0; s < 4; s++) {
        bf16x8 bf_ = *(const bf16x8*)&bsh[(s * 16 + lrow) * ST2 + ks * 32 + lk * 8];
        acc[s] = __builtin_amdgcn_mfma_f32_16x16x32_bf16(af, bf_, acc[s], 0, 0, 0);
      }
    }
    __syncthreads();
  }

  const float* rp = resid ? resid + (size_t)bi * cout * HW_ : nullptr;
  Tout* op = out + (size_t)bi * cout * HW_;
#pragma unroll
  for (int s = 0; s < 4; s++) {
#pragma unroll
    for (int r = 0; r < 4; r++) {
      int o = o0 + lk * 4 + r;
      int n = n0 + s * 16 + lrow;
      size_t off = (size_t)o * HW_ + n;
      float v = acc[s][r];
      if (rp) v += rp[off];
      if (accum) v += toF(op[off]);
      storeF(&op[off], v);
    }
  }
}

// ------- depthwise conv (bf16 in/out), fused L2 sum-of-squares for q,k -------
template <int K>
__global__ __launch_bounds__(256) void dwconv_d(const ushort_t* __restrict__ qkv0,
                                                const float* __restrict__ wq_,
                                                const float* __restrict__ wk_,
                                                const float* __restrict__ wv_,
                                                ushort_t* __restrict__ qd,
                                                ushort_t* __restrict__ kd,
                                                ushort_t* __restrict__ vd,
                                                float* __restrict__ sumsq_s) {
  constexpr int P = K / 2;
  __shared__ float wsh[K * K];
  __shared__ float red[4];
  int sel = blockIdx.y;
  const float* wgt = (sel == 0) ? wq_ : (sel == 1) ? wk_ : wv_;
  ushort_t* outp = (sel == 0) ? qd : (sel == 1) ? kd : vd;
  int blk = blockIdx.x;  // B*C*2
  int half = blk & 1;
  int c = (blk >> 1) & (C_ - 1);
  int bi = blk >> 8;
  int tid = threadIdx.x;

  if (tid < K * K) wsh[tid] = wgt[(size_t)c * K * K + tid];
  __syncthreads();

  int r = tid >> 3;
  int cb = (tid & 7) << 3;
  int y = half * 32 + r;
  const ushort_t* plane = qkv0 + ((size_t)bi * 384 + sel * C_ + c) * HW_;

  float a[8];
#pragma unroll
  for (int o = 0; o < 8; o++) a[o] = 0.f;
#pragma unroll
  for (int dy = 0; dy < K; dy++) {
    int gy = y + dy - P;
    if ((unsigned)gy < 64u) {
      float rv[16];
      loadrow_bf(plane + gy * 64, cb, rv);
#pragma unroll
      for (int dx = 0; dx < K; dx++) {
        float wv = wsh[dy * K + dx];
#pragma unroll
        for (int o = 0; o < 8; o++) a[o] = fmaf(rv[o + dx + 4 - P], wv, a[o]);
      }
    }
  }
  ushort_t* ob = outp + (size_t)(bi * C_ + c) * HW_ + y * 64 + cb;
  us4 t0, t1;
  t0.x = f2bu(a[0]); t0.y = f2bu(a[1]); t0.z = f2bu(a[2]); t0.w = f2bu(a[3]);
  t1.x = f2bu(a[4]); t1.y = f2bu(a[5]); t1.z = f2bu(a[6]); t1.w = f2bu(a[7]);
  *(us4*)ob = t0;
  *(us4*)(ob + 4) = t1;

  float ssq = 0.f;
#pragma unroll
  for (int o = 0; o < 8; o++) ssq = fmaf(a[o], a[o], ssq);
#pragma unroll
  for (int off = 32; off >= 1; off >>= 1) ssq += __shfl_xor(ssq, off, 64);
  if ((tid & 63) == 0) red[tid >> 6] = ssq;
  __syncthreads();
  if (tid == 0 && sel < 2) {
    atomicAdd(&sumsq_s[sel * 1024 + bi * C_ + c], red[0] + red[1] + red[2] + red[3]);
  }
}

// ------- FFN depthwise conv + GEGLU gate, 2x8 patch/thread (R15-proven) -------
template <int K>
__global__ __launch_bounds__(256) void ffn_dwgate_p(const ushort_t* __restrict__ xin,
                                                    const float* __restrict__ w,
                                                    ushort_t* __restrict__ gated) {
  constexpr int P = K / 2;
  __shared__ float wsh[2 * K * K];
  int blk = blockIdx.x;  // B*512
  int i = blk & 511;
  int bi = blk >> 9;
  int tid = threadIdx.x;

  if (tid < 2 * K * K) {
    wsh[tid] = (tid < K * K) ? w[(size_t)i * K * K + tid]
                             : w[(size_t)(512 + i) * K * K + (tid - K * K)];
  }
  __syncthreads();

  int r2 = tid >> 3;          // 0..31
  int cb = (tid & 7) << 3;
  int y0 = r2 * 2;
  const ushort_t* gin = xin + (size_t)(bi * 1024 + i) * HW_;
  const ushort_t* min_ = gin + (size_t)512 * HW_;

  float ge[16];
  {
    float a0[8], a1[8];
#pragma unroll
    for (int o = 0; o < 8; o++) { a0[o] = 0.f; a1[o] = 0.f; }
#pragma unroll
    for (int rr = 0; rr <= K; rr++) {
      int gy = y0 - P + rr;
      if ((unsigned)gy < 64u) {
        float rv[16];
        loadrow_bf(gin + gy * 64, cb, rv);
        if (rr < K) {
          float wv;
#pragma unroll
          for (int dx = 0; dx < K; dx++) {
            wv = wsh[rr * K + dx];
#pragma unroll
            for (int o = 0; o < 8; o++) a0[o] = fmaf(rv[o + dx + 4 - P], wv, a0[o]);
          }
        }
        if (rr >= 1) {
          float wv;
#pragma unroll
          for (int dx = 0; dx < K; dx++) {
            wv = wsh[(rr - 1) * K + dx];
#pragma unroll
            for (int o = 0; o < 8; o++) a1[o] = fmaf(rv[o + dx + 4 - P], wv, a1[o]);
          }
        }
      }
    }
#pragma unroll
    for (int o = 0; o < 8; o++) { ge[o] = gelu_t(a0[o]); ge[8 + o] = gelu_t(a1[o]); }
  }

  float m0[8], m1[8];
#pragma unroll
  for (int o = 0; o < 8; o++) { m0[o] = 0.f; m1[o] = 0.f; }
#pragma unroll
  for (int rr = 0; rr <= K; rr++) {
    int gy = y0 - P + rr;
    if ((unsigned)gy < 64u) {
      float rv[16];
      loadrow_bf(min_ + gy * 64, cb, rv);
      if (rr < K) {
        float wv;
#pragma unroll
        for (int dx = 0; dx < K; dx++) {
          wv = wsh[K * K + rr * K + dx];
#pragma unroll
          for (int o = 0; o < 8; o++) m0[o] = fmaf(rv[o + dx + 4 - P], wv, m0[o]);
        }
      }
      if (rr >= 1) {
        float wv;
#pragma unroll
        for (int dx = 0; dx < K; dx++) {
          wv = wsh[K * K + (rr - 1) * K + dx];
#pragma unroll
          for (int o = 0; o < 8; o++) m1[o] = fmaf(rv[o + dx + 4 - P], wv, m1[o]);
        }
      }
    }
  }
  ushort_t* gp = gated + (size_t)(bi * 512 + i) * HW_ + y0 * 64 + cb;
#pragma unroll
  for (int v = 0; v < 2; v++) {
    us4 t;
    t.x = f2bu(ge[v * 4 + 0] * m0[v * 4 + 0]);
    t.y = f2bu(ge[v * 4 + 1] * m0[v * 4 + 1]);
    t.z = f2bu(ge[v * 4 + 2] * m0[v * 4 + 2]);
    t.w = f2bu(ge[v * 4 + 3] * m0[v * 4 + 3]);
    *(us4*)(gp + v * 4) = t;
  }
  gp += 64;
#pragma unroll
  for (int v = 0; v < 2; v++) {
    us4 t;
    t.x = f2bu(ge[8 + v * 4 + 0] * m1[v * 4 + 0]);
    t.y = f2bu(ge[8 + v * 4 + 1] * m1[v * 4 + 1]);
    t.z = f2bu(ge[8 + v * 4 + 2] * m1[v * 4 + 2]);
    t.w = f2bu(ge[8 + v * 4 + 3] * m1[v * 4 + 3]);
    *(us4*)(gp + v * 4) = t;
  }
}

// ---------------- attention: partial scores over 256-position chunks (bf16 in) ----------------
__global__ __launch_bounds__(256) void attn_score_part(const ushort_t* __restrict__ qd,
                                                       const ushort_t* __restrict__ kd,
                                                       float* __restrict__ part) {
  constexpr int ST = 258;
  __shared__ float qs[16 * ST];
  __shared__ float ks[16 * ST];
  int bh = blockIdx.x;   // 64
  int ch = blockIdx.y;   // 16 chunks of 256
  int bi = bh >> 3;
  int h = bh & 7;
  int tid = threadIdx.x;
  int c = tid >> 4;
  int d = tid & 15;

  const ushort_t* qrow = qd + (size_t)(bi * C_ + h * CH_) * HW_ + ch * 256;
  const ushort_t* krow = kd + (size_t)(bi * C_ + h * CH_) * HW_ + ch * 256;
#pragma unroll
  for (int it = 0; it < 4; it++) {
    int idx = tid + it * 256;
    int r = idx >> 6, q4 = idx & 63;
    us4 qv = *(const us4*)(qrow + (size_t)r * HW_ + q4 * 4);
    us4 kv = *(const us4*)(krow + (size_t)r * HW_ + q4 * 4);
    float* qdst = &qs[r * ST + q4 * 4];
    float* kdst = &ks[r * ST + q4 * 4];
    qdst[0] = bf2f(qv.x); qdst[1] = bf2f(qv.y); qdst[2] = bf2f(qv.z); qdst[3] = bf2f(qv.w);
    kdst[0] = bf2f(kv.x); kdst[1] = bf2f(kv.y); kdst[2] = bf2f(kv.z); kdst[3] = bf2f(kv.w);
  }
  __syncthreads();

  const float* qp = &qs[c * ST];
  const float* kp = &ks[d * ST];
  float acc = 0.f;
#pragma unroll 8
  for (int j = 0; j < 256; j++) acc = fmaf(qp[j], kp[j], acc);
  part[((size_t)bh * 16 + ch) * 256 + tid] = acc;
}

// ------- attention: fused softmax + PV; writes merged osb_all [bi][384][HW] -------
__global__ __launch_bounds__(256) void attn_pv_sm(const ushort_t* __restrict__ vd,
                                                  const float* __restrict__ part,
                                                  const float* __restrict__ sumsq_s,
                                                  const float* __restrict__ temp,
                                                  ushort_t* __restrict__ osb_all,
                                                  int coff) {
  __shared__ float as[16][17];
  int bh = blockIdx.x;  // 64
  int ch = blockIdx.y;  // 16
  int bi = bh >> 3;
  int h = bh & 7;
  int tid = threadIdx.x;

  {
    int c = tid >> 4;
    int d = tid & 15;
    float s = 0.f;
    const float* pp = part + (size_t)bh * 16 * 256 + tid;
#pragma unroll
    for (int c2 = 0; c2 < 16; c2++) s += pp[c2 * 256];
    float sq = sumsq_s[bi * C_ + h * CH_ + c];
    float sk = sumsq_s[1024 + bi * C_ + h * CH_ + d];
    float invq = 1.f / fmaxf(sqrtf(sq), 1e-12f);
    float invk = 1.f / fmaxf(sqrtf(sk), 1e-12f);
    float S = s * invq * invk * temp[h];
    float mx = S;
#pragma unroll
    for (int o = 8; o >= 1; o >>= 1) mx = fmaxf(mx, __shfl_xor(mx, o, 16));
    float e = expf(S - mx);
    float sm = e;
#pragma unroll
    for (int o = 8; o >= 1; o >>= 1) sm += __shfl_xor(sm, o, 16);
    as[c][d] = e / sm;
  }
  __syncthreads();

  int n = ch * 256 + tid;
  const ushort_t* vrow = vd + (size_t)(bi * C_ + h * CH_) * HW_ + n;
  float o_[16];
#pragma unroll
  for (int cc = 0; cc < 16; cc++) o_[cc] = 0.f;
#pragma unroll
  for (int dd = 0; dd < 16; dd++) {
    float vv = bf2f(vrow[(size_t)dd * HW_]);
#pragma unroll
    for (int cc = 0; cc < 16; cc++) o_[cc] = fmaf(as[cc][dd], vv, o_[cc]);
  }
  ushort_t* ob = osb_all + ((size_t)bi * 384 + coff + h * CH_) * HW_ + n;
#pragma unroll
  for (int cc = 0; cc < 16; cc++) ob[(size_t)cc * HW_] = f2bu(o_[cc]);
}

extern "C" void kernel_launch(void* const* d_in, const int* in_sizes, int n_in,
                              void* d_out, int out_size, void* d_ws, size_t ws_size,
                              hipStream_t stream) {
  const float* x = (const float*)d_in[0];
  const float* ln1_w = (const float*)d_in[1];
  const float* ln1_b = (const float*)d_in[2];
  const float* temp = (const float*)d_in[3];
  const float* wq = (const float*)d_in[4];
  const float* wk = (const float*)d_in[5];
  const float* wv = (const float*)d_in[6];
  const float* dw[9];
  for (int i = 0; i < 9; i++) dw[i] = (const float*)d_in[7 + i];
  const float* attn_po = (const float*)d_in[16];
  const float* ln2_w = (const float*)d_in[17];
  const float* ln2_b = (const float*)d_in[18];
  const float* ffn_in = (const float*)d_in[19];
  const float* ffn_dw[3] = {(const float*)d_in[20], (const float*)d_in[21],
                            (const float*)d_in[22]};
  const float* ffn_po = (const float*)d_in[23];
  float* out = (float*)d_out;

  // ---- workspace layout (bf16 intermediates), lifetime-aliased ----
  const size_t MB = (size_t)1 << 20;
  char* wsb = (char*)d_ws;
  ushort_t* xnb = (ushort_t*)(wsb + 0 * MB);
  float* part = (float*)(wsb + 0 * MB);  // 1MB; xnb dead when used
  ushort_t* qkv0 = (ushort_t*)(wsb + 16 * MB);     // 24MB
  ushort_t* qdb = (ushort_t*)(wsb + 40 * MB);      // 8MB
  ushort_t* kdb = (ushort_t*)(wsb + 48 * MB);
  ushort_t* vdb = (ushort_t*)(wsb + 56 * MB);
  ushort_t* osb_all = (ushort_t*)(wsb + 64 * MB);  // 24MB
  float* x2 = (float*)(wsb + 112 * MB);            // 16MB
  float* sumsq = (float*)(wsb + 128 * MB);                   // 24 KiB
  ushort_t* wbuf = (ushort_t*)(wsb + 128 * MB + 32 * 1024);  // 832 KiB
  ushort_t* xin = (ushort_t*)(wsb + 16 * MB);      // 64MB (attn buffers dead)
  ushort_t* gated = (ushort_t*)(wsb + 80 * MB);    // 32MB

  const ushort_t* wb_qkv = wbuf;            // [384][128]
  const ushort_t* wb_apo = wbuf + 49152;    // [128][384]
  const ushort_t* wb_fin = wbuf + 98304;    // [1024][128]
  const ushort_t* wb_fpo = wbuf + 229376;   // [128][1536]

  const int ln_grid = (B_ * HW_) / 64;                   // 512 (v2: 64 pos/block)
  const int g_qkv = B_ * (384 / 64) * 64;                // 3072
  const int g128 = B_ * (C_ / 64) * 64;                  // 1024
  const int g1024 = B_ * (1024 / 64) * 64;               // 8192
  const dim3 dwt_grid(B_ * C_ * 2, 3);                   // 2048 x 3
  const int ffg_grid = B_ * 512;                         // 4096
  const dim3 att_grid(B_ * HEADS_, 16);                  // 64 x 16

  // ---- prep ----
  hipMemsetAsync(sumsq, 0, 3 * 2048 * sizeof(float), stream);
  cvt_w<<<1664, 256, 0, stream>>>(wq, wk, wv, attn_po, ffn_in, ffn_po, wbuf);

  // ---- attention branch ----
  ln_ch<<<ln_grid, 256, 0, stream>>>(x, ln1_w, ln1_b, xnb);
  conv1x1_m<ushort_t, ushort_t><<<g_qkv, 256, 0, stream>>>(
      xnb, wb_qkv, nullptr, qkv0, C_, 384, C_, 0);

  for (int s = 0; s < 3; s++) {
    float* sumsq_s = sumsq + s * 2048;
    if (s == 0)
      dwconv_d<3><<<dwt_grid, 256, 0, stream>>>(qkv0, dw[0], dw[1], dw[2],
                                                qdb, kdb, vdb, sumsq_s);
    else if (s == 1)
      dwconv_d<5><<<dwt_grid, 256, 0, stream>>>(qkv0, dw[3], dw[4], dw[5],
                                                qdb, kdb, vdb, sumsq_s);
    else
      dwconv_d<7><<<dwt_grid, 256, 0, stream>>>(qkv0, dw[6], dw[7], dw[8],
                                                qdb, kdb, vdb, sumsq_s);
    attn_score_part<<<att_grid, 256, 0, stream>>>(qdb, kdb, part);
    attn_pv_sm<<<att_grid, 256, 0, stream>>>(vdb, part, sumsq_s, temp, osb_all,
                                             s * C_);
  }
  // single merged attn_po GEMM: x2 = x + attn_po @ osb_all (cin=384)
  conv1x1_m<ushort_t, float><<<g128, 256, 0, stream>>>(
      osb_all, wb_apo, x, x2, 384, C_, 384, 0);

  // ---- FFN branch ----
  ln_ch<<<ln_grid, 256, 0, stream>>>(x2, ln2_w, ln2_b, xnb);
  conv1x1_m<ushort_t, ushort_t><<<g1024, 256, 0, stream>>>(
      xnb, wb_fin, nullptr, xin, C_, 1024, C_, 0);

  for (int s = 0; s < 3; s++) {
    if (s == 0)
      ffn_dwgate_p<3><<<ffg_grid, 256, 0, stream>>>(xin, ffn_dw[0], gated);
    else if (s == 1)
      ffn_dwgate_p<5><<<ffg_grid, 256, 0, stream>>>(xin, ffn_dw[1], gated);
    else
      ffn_dwgate_p<7><<<ffg_grid, 256, 0, stream>>>(xin, ffn_dw[2], gated);
    conv1x1_m<ushort_t, float><<<g128, 256, 0, stream>>>(
        gated, wb_fpo + s * 512, (s == 0) ? x2 : nullptr, out, 512, C_, 3 * HID_,
        s == 0 ? 0 : 1);
  }
  (void)in_sizes; (void)n_in; (void)out_size; (void)ws_size;
}

// Round 21
// 395.538 us; speedup vs baseline: 1.1950x; 1.0814x over previous
//
#include <hip/hip_runtime.h>
#include <hip/hip_bf16.h>
#include <math.h>

#define B_ 8
#define C_ 128
#define H_ 64
#define W_ 64
#define HW_ 4096
#define HEADS_ 8
#define CH_ 16
#define HID_ 512

typedef unsigned short ushort_t;
struct __attribute__((aligned(8))) us4 { ushort_t x, y, z, w; };

typedef __attribute__((ext_vector_type(8))) short bf16x8;
typedef __attribute__((ext_vector_type(4))) float f32x4;

__device__ __forceinline__ float bf2f(ushort_t u) {
  return __uint_as_float(((unsigned int)u) << 16);
}
__device__ __forceinline__ ushort_t f2bu(float f) {
  __hip_bfloat16 h = __float2bfloat16(f);
  return *reinterpret_cast<ushort_t*>(&h);
}
__device__ __forceinline__ float toF(float v) { return v; }
__device__ __forceinline__ float toF(ushort_t v) { return bf2f(v); }
__device__ __forceinline__ void storeF(float* p, float v) { *p = v; }
__device__ __forceinline__ void storeF(ushort_t* p, float v) { *p = f2bu(v); }

// tanh-GELU: max dev from exact erf-GELU ~1e-3, straight-line
__device__ __forceinline__ float gelu_t(float x) {
  float z = 0.7978845608f * fmaf(0.044715f * x, x * x, x);
  float e = __expf(2.f * z);
  float th = 1.f - 2.f / (e + 1.f);
  return 0.5f * x * (1.f + th);
}

// ------- LayerNorm over channel dim (bf16 out), v2: 64 pos/block x 4 ch-groups -------
__global__ __launch_bounds__(256) void ln_ch(const float* __restrict__ x,
                                             const float* __restrict__ w,
                                             const float* __restrict__ b,
                                             ushort_t* __restrict__ out) {
  __shared__ float rs[4][64];
  __shared__ float rss[4][64];
  int tid = threadIdx.x;
  int pl = tid & 63;
  int cg = tid >> 6;
  int p = blockIdx.x * 64 + pl;  // over B*HW
  int bi = p >> 12;
  int pos = p & (HW_ - 1);
  const float* xb = x + (size_t)bi * C_ * HW_ + pos;
  float s = 0.f, ss = 0.f;
#pragma unroll 8
  for (int c = 0; c < 32; c++) {
    float v = xb[(size_t)(cg * 32 + c) * HW_];
    s += v;
    ss = fmaf(v, v, ss);
  }
  rs[cg][pl] = s;
  rss[cg][pl] = ss;
  __syncthreads();
  float ts = rs[0][pl] + rs[1][pl] + rs[2][pl] + rs[3][pl];
  float tss = rss[0][pl] + rss[1][pl] + rss[2][pl] + rss[3][pl];
  float mu = ts * (1.f / C_);
  float var = tss * (1.f / C_) - mu * mu;
  float inv = rsqrtf(var + 1e-5f);
  ushort_t* ob = out + (size_t)bi * C_ * HW_ + pos;
#pragma unroll 8
  for (int c = 0; c < 32; c++) {
    int ch = cg * 32 + c;
    ob[(size_t)ch * HW_] = f2bu((xb[(size_t)ch * HW_] - mu) * inv * w[ch] + b[ch]);
  }
}

// ---------------- weight prep: fp32 -> bf16, all six matrices ----------------
__global__ __launch_bounds__(256) void cvt_w(const float* __restrict__ wq,
                                             const float* __restrict__ wk,
                                             const float* __restrict__ wv,
                                             const float* __restrict__ apo,
                                             const float* __restrict__ fin,
                                             const float* __restrict__ fpo,
                                             ushort_t* __restrict__ dst) {
  int id = blockIdx.x * 256 + threadIdx.x;
  const float* src;
  int off;
  if (id < 16384) { src = wq; off = id; }
  else if (id < 32768) { src = wk; off = id - 16384; }
  else if (id < 49152) { src = wv; off = id - 32768; }
  else if (id < 98304) { src = apo; off = id - 49152; }
  else if (id < 229376) { src = fin; off = id - 98304; }
  else if (id < 425984) { src = fpo; off = id - 229376; }
  else return;
  dst[id] = f2bu(src[off]);
}

// ------- shfl-halo row load: rv[j] = row[cb-4+j], j=0..15, zero pad at edges -------
// Own 8 elems = 2 unconditional uint2 loads; halos from neighbor lanes via shfl.
// Row-group = 8 lanes (lane7 = tid&7); group boundaries masked to zero (== old
// out-of-range zeroing). Shfl sources within a group are always active lanes.
__device__ __forceinline__ void loadrow_sh(const ushort_t* __restrict__ rowp,
                                           int cb, int lane7, float* rv) {
  uint2 a = *(const uint2*)(rowp + cb);      // row[cb..cb+3]
  uint2 b = *(const uint2*)(rowp + cb + 4);  // row[cb+4..cb+7]
  unsigned l0 = __shfl_up(b.x, 1, 64);
  unsigned l1 = __shfl_up(b.y, 1, 64);
  unsigned r0 = __shfl_down(a.x, 1, 64);
  unsigned r1 = __shfl_down(a.y, 1, 64);
  if (lane7 == 0) { l0 = 0u; l1 = 0u; }
  if (lane7 == 7) { r0 = 0u; r1 = 0u; }
  rv[0]  = __uint_as_float(l0 << 16);  rv[1]  = __uint_as_float(l0 & 0xffff0000u);
  rv[2]  = __uint_as_float(l1 << 16);  rv[3]  = __uint_as_float(l1 & 0xffff0000u);
  rv[4]  = __uint_as_float(a.x << 16); rv[5]  = __uint_as_float(a.x & 0xffff0000u);
  rv[6]  = __uint_as_float(a.y << 16); rv[7]  = __uint_as_float(a.y & 0xffff0000u);
  rv[8]  = __uint_as_float(b.x << 16); rv[9]  = __uint_as_float(b.x & 0xffff0000u);
  rv[10] = __uint_as_float(b.y << 16); rv[11] = __uint_as_float(b.y & 0xffff0000u);
  rv[12] = __uint_as_float(r0 << 16);  rv[13] = __uint_as_float(r0 & 0xffff0000u);
  rv[14] = __uint_as_float(r1 << 16);  rv[15] = __uint_as_float(r1 & 0xffff0000u);
}

// ------- conv1x1 as bf16 MFMA GEMM: Out[cout][HW] = W[cout][cin] @ In[cin][HW] -------
// Transposed LDS tile [n][k]; staging = per-thread scalar global loads packed into
// one ds_write_b64 (R14/R16-proven).
template <typename Tin, typename Tout>
__global__ __launch_bounds__(256) void conv1x1_m(const Tin* __restrict__ in,
                                                 const ushort_t* __restrict__ wtb,
                                                 const float* __restrict__ resid,
                                                 Tout* __restrict__ out,
                                                 int cin, int cout, int wstride,
                                                 int accum) {
  constexpr int ST2 = 136;
  __shared__ ushort_t bsh[64 * ST2];
  int tid = threadIdx.x;
  int lane = tid & 63;
  int wid = tid >> 6;
  int lrow = lane & 15;
  int lk = lane >> 4;
  int blk = blockIdx.x;
  int nb = blk & 63;
  int rest = blk >> 6;
  int mb = cout >> 6;
  int m = rest % mb;
  int bi = rest / mb;
  int n0 = nb << 6;
  int o0 = (m << 6) + wid * 16;

  f32x4 acc[4] = {{0.f, 0.f, 0.f, 0.f}, {0.f, 0.f, 0.f, 0.f},
                  {0.f, 0.f, 0.f, 0.f}, {0.f, 0.f, 0.f, 0.f}};

  int nn = tid & 63;
  int wk4 = tid >> 6;
  for (int kc = 0; kc < cin; kc += 128) {
#pragma unroll
    for (int p = 0; p < 8; p++) {
      int kb = p * 16 + wk4 * 4;
      ushort_t u[4];
#pragma unroll
      for (int j = 0; j < 4; j++) {
        const Tin* src = in + ((size_t)bi * cin + kc + kb + j) * HW_ + n0 + nn;
        if constexpr (sizeof(Tin) == 4) {
          u[j] = f2bu(*(const float*)src);
        } else {
          u[j] = *(const ushort_t*)src;
        }
      }
      us4 w4;
      w4.x = u[0]; w4.y = u[1]; w4.z = u[2]; w4.w = u[3];
      *(us4*)&bsh[nn * ST2 + kb] = w4;
    }
    __syncthreads();
#pragma unroll
    for (int ks = 0; ks < 4; ks++) {
      const ushort_t* wr = wtb + (size_t)(o0 + lrow) * wstride + kc + ks * 32 + lk * 8;
      us4 wlo = *(const us4*)wr;
      us4 whi = *(const us4*)(wr + 4);
      bf16x8 af;
      af[0] = (short)wlo.x; af[1] = (short)wlo.y;
      af[2] = (short)wlo.z; af[3] = (short)wlo.w;
      af[4] = (short)whi.x; af[5] = (short)whi.y;
      af[6] = (short)whi.z; af[7] = (short)whi.w;
#pragma unroll
      for (int s = 0; s < 4; s++) {
        bf16x8 bf_ = *(const bf16x8*)&bsh[(s * 16 + lrow) * ST2 + ks * 32 + lk * 8];
        acc[s] = __builtin_amdgcn_mfma_f32_16x16x32_bf16(af, bf_, acc[s], 0, 0, 0);
      }
    }
    __syncthreads();
  }

  const float* rp = resid ? resid + (size_t)bi * cout * HW_ : nullptr;
  Tout* op = out + (size_t)bi * cout * HW_;
#pragma unroll
  for (int s = 0; s < 4; s++) {
#pragma unroll
    for (int r = 0; r < 4; r++) {
      int o = o0 + lk * 4 + r;
      int n = n0 + s * 16 + lrow;
      size_t off = (size_t)o * HW_ + n;
      float v = acc[s][r];
      if (rp) v += rp[off];
      if (accum) v += toF(op[off]);
      storeF(&op[off], v);
    }
  }
}

// ------- depthwise conv (bf16 in/out), fused L2 sum-of-squares, shfl-halo loads -------
template <int K>
__global__ __launch_bounds__(256) void dwconv_d(const ushort_t* __restrict__ qkv0,
                                                const float* __restrict__ wq_,
                                                const float* __restrict__ wk_,
                                                const float* __restrict__ wv_,
                                                ushort_t* __restrict__ qd,
                                                ushort_t* __restrict__ kd,
                                                ushort_t* __restrict__ vd,
                                                float* __restrict__ sumsq_s) {
  constexpr int P = K / 2;
  __shared__ float wsh[K * K];
  __shared__ float red[4];
  int sel = blockIdx.y;
  const float* wgt = (sel == 0) ? wq_ : (sel == 1) ? wk_ : wv_;
  ushort_t* outp = (sel == 0) ? qd : (sel == 1) ? kd : vd;
  int blk = blockIdx.x;  // B*C*2
  int half = blk & 1;
  int c = (blk >> 1) & (C_ - 1);
  int bi = blk >> 8;
  int tid = threadIdx.x;

  if (tid < K * K) wsh[tid] = wgt[(size_t)c * K * K + tid];
  __syncthreads();

  int r = tid >> 3;
  int lane7 = tid & 7;
  int cb = lane7 << 3;
  int y = half * 32 + r;
  const ushort_t* plane = qkv0 + ((size_t)bi * 384 + sel * C_ + c) * HW_;

  float a[8];
#pragma unroll
  for (int o = 0; o < 8; o++) a[o] = 0.f;
#pragma unroll
  for (int dy = 0; dy < K; dy++) {
    int gy = y + dy - P;
    if ((unsigned)gy < 64u) {
      float rv[16];
      loadrow_sh(plane + gy * 64, cb, lane7, rv);
#pragma unroll
      for (int dx = 0; dx < K; dx++) {
        float wv = wsh[dy * K + dx];
#pragma unroll
        for (int o = 0; o < 8; o++) a[o] = fmaf(rv[o + dx + 4 - P], wv, a[o]);
      }
    }
  }
  ushort_t* ob = outp + (size_t)(bi * C_ + c) * HW_ + y * 64 + cb;
  us4 t0, t1;
  t0.x = f2bu(a[0]); t0.y = f2bu(a[1]); t0.z = f2bu(a[2]); t0.w = f2bu(a[3]);
  t1.x = f2bu(a[4]); t1.y = f2bu(a[5]); t1.z = f2bu(a[6]); t1.w = f2bu(a[7]);
  *(us4*)ob = t0;
  *(us4*)(ob + 4) = t1;

  float ssq = 0.f;
#pragma unroll
  for (int o = 0; o < 8; o++) ssq = fmaf(a[o], a[o], ssq);
#pragma unroll
  for (int off = 32; off >= 1; off >>= 1) ssq += __shfl_xor(ssq, off, 64);
  if ((tid & 63) == 0) red[tid >> 6] = ssq;
  __syncthreads();
  if (tid == 0 && sel < 2) {
    atomicAdd(&sumsq_s[sel * 1024 + bi * C_ + c], red[0] + red[1] + red[2] + red[3]);
  }
}

// ------- FFN depthwise conv + GEGLU gate, 2x8 patch/thread, shfl-halo loads -------
template <int K>
__global__ __launch_bounds__(256) void ffn_dwgate_p(const ushort_t* __restrict__ xin,
                                                    const float* __restrict__ w,
                                                    ushort_t* __restrict__ gated) {
  constexpr int P = K / 2;
  __shared__ float wsh[2 * K * K];
  int blk = blockIdx.x;  // B*512
  int i = blk & 511;
  int bi = blk >> 9;
  int tid = threadIdx.x;

  if (tid < 2 * K * K) {
    wsh[tid] = (tid < K * K) ? w[(size_t)i * K * K + tid]
                             : w[(size_t)(512 + i) * K * K + (tid - K * K)];
  }
  __syncthreads();

  int r2 = tid >> 3;          // 0..31
  int lane7 = tid & 7;
  int cb = lane7 << 3;
  int y0 = r2 * 2;
  const ushort_t* gin = xin + (size_t)(bi * 1024 + i) * HW_;
  const ushort_t* min_ = gin + (size_t)512 * HW_;

  float ge[16];
  {
    float a0[8], a1[8];
#pragma unroll
    for (int o = 0; o < 8; o++) { a0[o] = 0.f; a1[o] = 0.f; }
#pragma unroll
    for (int rr = 0; rr <= K; rr++) {
      int gy = y0 - P + rr;
      if ((unsigned)gy < 64u) {
        float rv[16];
        loadrow_sh(gin + gy * 64, cb, lane7, rv);
        if (rr < K) {
          float wv;
#pragma unroll
          for (int dx = 0; dx < K; dx++) {
            wv = wsh[rr * K + dx];
#pragma unroll
            for (int o = 0; o < 8; o++) a0[o] = fmaf(rv[o + dx + 4 - P], wv, a0[o]);
          }
        }
        if (rr >= 1) {
          float wv;
#pragma unroll
          for (int dx = 0; dx < K; dx++) {
            wv = wsh[(rr - 1) * K + dx];
#pragma unroll
            for (int o = 0; o < 8; o++) a1[o] = fmaf(rv[o + dx + 4 - P], wv, a1[o]);
          }
        }
      }
    }
#pragma unroll
    for (int o = 0; o < 8; o++) { ge[o] = gelu_t(a0[o]); ge[8 + o] = gelu_t(a1[o]); }
  }

  float m0[8], m1[8];
#pragma unroll
  for (int o = 0; o < 8; o++) { m0[o] = 0.f; m1[o] = 0.f; }
#pragma unroll
  for (int rr = 0; rr <= K; rr++) {
    int gy = y0 - P + rr;
    if ((unsigned)gy < 64u) {
      float rv[16];
      loadrow_sh(min_ + gy * 64, cb, lane7, rv);
      if (rr < K) {
        float wv;
#pragma unroll
        for (int dx = 0; dx < K; dx++) {
          wv = wsh[K * K + rr * K + dx];
#pragma unroll
          for (int o = 0; o < 8; o++) m0[o] = fmaf(rv[o + dx + 4 - P], wv, m0[o]);
        }
      }
      if (rr >= 1) {
        float wv;
#pragma unroll
        for (int dx = 0; dx < K; dx++) {
          wv = wsh[K * K + (rr - 1) * K + dx];
#pragma unroll
          for (int o = 0; o < 8; o++) m1[o] = fmaf(rv[o + dx + 4 - P], wv, m1[o]);
        }
      }
    }
  }
  ushort_t* gp = gated + (size_t)(bi * 512 + i) * HW_ + y0 * 64 + cb;
#pragma unroll
  for (int v = 0; v < 2; v++) {
    us4 t;
    t.x = f2bu(ge[v * 4 + 0] * m0[v * 4 + 0]);
    t.y = f2bu(ge[v * 4 + 1] * m0[v * 4 + 1]);
    t.z = f2bu(ge[v * 4 + 2] * m0[v * 4 + 2]);
    t.w = f2bu(ge[v * 4 + 3] * m0[v * 4 + 3]);
    *(us4*)(gp + v * 4) = t;
  }
  gp += 64;
#pragma unroll
  for (int v = 0; v < 2; v++) {
    us4 t;
    t.x = f2bu(ge[8 + v * 4 + 0] * m1[v * 4 + 0]);
    t.y = f2bu(ge[8 + v * 4 + 1] * m1[v * 4 + 1]);
    t.z = f2bu(ge[8 + v * 4 + 2] * m1[v * 4 + 2]);
    t.w = f2bu(ge[8 + v * 4 + 3] * m1[v * 4 + 3]);
    *(us4*)(gp + v * 4) = t;
  }
}

// ---------------- attention: partial scores over 256-position chunks (bf16 in) ----------------
__global__ __launch_bounds__(256) void attn_score_part(const ushort_t* __restrict__ qd,
                                                       const ushort_t* __restrict__ kd,
                                                       float* __restrict__ part) {
  constexpr int ST = 258;
  __shared__ float qs[16 * ST];
  __shared__ float ks[16 * ST];
  int bh = blockIdx.x;   // 64
  int ch = blockIdx.y;   // 16 chunks of 256
  int bi = bh >> 3;
  int h = bh & 7;
  int tid = threadIdx.x;
  int c = tid >> 4;
  int d = tid & 15;

  const ushort_t* qrow = qd + (size_t)(bi * C_ + h * CH_) * HW_ + ch * 256;
  const ushort_t* krow = kd + (size_t)(bi * C_ + h * CH_) * HW_ + ch * 256;
#pragma unroll
  for (int it = 0; it < 4; it++) {
    int idx = tid + it * 256;
    int r = idx >> 6, q4 = idx & 63;
    us4 qv = *(const us4*)(qrow + (size_t)r * HW_ + q4 * 4);
    us4 kv = *(const us4*)(krow + (size_t)r * HW_ + q4 * 4);
    float* qdst = &qs[r * ST + q4 * 4];
    float* kdst = &ks[r * ST + q4 * 4];
    qdst[0] = bf2f(qv.x); qdst[1] = bf2f(qv.y); qdst[2] = bf2f(qv.z); qdst[3] = bf2f(qv.w);
    kdst[0] = bf2f(kv.x); kdst[1] = bf2f(kv.y); kdst[2] = bf2f(kv.z); kdst[3] = bf2f(kv.w);
  }
  __syncthreads();

  const float* qp = &qs[c * ST];
  const float* kp = &ks[d * ST];
  float acc = 0.f;
#pragma unroll 8
  for (int j = 0; j < 256; j++) acc = fmaf(qp[j], kp[j], acc);
  part[((size_t)bh * 16 + ch) * 256 + tid] = acc;
}

// ------- attention: fused softmax + PV; writes merged osb_all [bi][384][HW] -------
__global__ __launch_bounds__(256) void attn_pv_sm(const ushort_t* __restrict__ vd,
                                                  const float* __restrict__ part,
                                                  const float* __restrict__ sumsq_s,
                                                  const float* __restrict__ temp,
                                                  ushort_t* __restrict__ osb_all,
                                                  int coff) {
  __shared__ float as[16][17];
  int bh = blockIdx.x;  // 64
  int ch = blockIdx.y;  // 16
  int bi = bh >> 3;
  int h = bh & 7;
  int tid = threadIdx.x;

  {
    int c = tid >> 4;
    int d = tid & 15;
    float s = 0.f;
    const float* pp = part + (size_t)bh * 16 * 256 + tid;
#pragma unroll
    for (int c2 = 0; c2 < 16; c2++) s += pp[c2 * 256];
    float sq = sumsq_s[bi * C_ + h * CH_ + c];
    float sk = sumsq_s[1024 + bi * C_ + h * CH_ + d];
    float invq = 1.f / fmaxf(sqrtf(sq), 1e-12f);
    float invk = 1.f / fmaxf(sqrtf(sk), 1e-12f);
    float S = s * invq * invk * temp[h];
    float mx = S;
#pragma unroll
    for (int o = 8; o >= 1; o >>= 1) mx = fmaxf(mx, __shfl_xor(mx, o, 16));
    float e = expf(S - mx);
    float sm = e;
#pragma unroll
    for (int o = 8; o >= 1; o >>= 1) sm += __shfl_xor(sm, o, 16);
    as[c][d] = e / sm;
  }
  __syncthreads();

  int n = ch * 256 + tid;
  const ushort_t* vrow = vd + (size_t)(bi * C_ + h * CH_) * HW_ + n;
  float o_[16];
#pragma unroll
  for (int cc = 0; cc < 16; cc++) o_[cc] = 0.f;
#pragma unroll
  for (int dd = 0; dd < 16; dd++) {
    float vv = bf2f(vrow[(size_t)dd * HW_]);
#pragma unroll
    for (int cc = 0; cc < 16; cc++) o_[cc] = fmaf(as[cc][dd], vv, o_[cc]);
  }
  ushort_t* ob = osb_all + ((size_t)bi * 384 + coff + h * CH_) * HW_ + n;
#pragma unroll
  for (int cc = 0; cc < 16; cc++) ob[(size_t)cc * HW_] = f2bu(o_[cc]);
}

extern "C" void kernel_launch(void* const* d_in, const int* in_sizes, int n_in,
                              void* d_out, int out_size, void* d_ws, size_t ws_size,
                              hipStream_t stream) {
  const float* x = (const float*)d_in[0];
  const float* ln1_w = (const float*)d_in[1];
  const float* ln1_b = (const float*)d_in[2];
  const float* temp = (const float*)d_in[3];
  const float* wq = (const float*)d_in[4];
  const float* wk = (const float*)d_in[5];
  const float* wv = (const float*)d_in[6];
  const float* dw[9];
  for (int i = 0; i < 9; i++) dw[i] = (const float*)d_in[7 + i];
  const float* attn_po = (const float*)d_in[16];
  const float* ln2_w = (const float*)d_in[17];
  const float* ln2_b = (const float*)d_in[18];
  const float* ffn_in = (const float*)d_in[19];
  const float* ffn_dw[3] = {(const float*)d_in[20], (const float*)d_in[21],
                            (const float*)d_in[22]};
  const float* ffn_po = (const float*)d_in[23];
  float* out = (float*)d_out;

  // ---- workspace layout (bf16 intermediates), lifetime-aliased ----
  const size_t MB = (size_t)1 << 20;
  char* wsb = (char*)d_ws;
  ushort_t* xnb = (ushort_t*)(wsb + 0 * MB);
  float* part = (float*)(wsb + 0 * MB);  // 1MB; xnb dead when used
  ushort_t* qkv0 = (ushort_t*)(wsb + 16 * MB);     // 24MB
  ushort_t* qdb = (ushort_t*)(wsb + 40 * MB);      // 8MB
  ushort_t* kdb = (ushort_t*)(wsb + 48 * MB);
  ushort_t* vdb = (ushort_t*)(wsb + 56 * MB);
  ushort_t* osb_all = (ushort_t*)(wsb + 64 * MB);  // 24MB
  float* x2 = (float*)(wsb + 112 * MB);            // 16MB
  float* sumsq = (float*)(wsb + 128 * MB);                   // 24 KiB
  ushort_t* wbuf = (ushort_t*)(wsb + 128 * MB + 32 * 1024);  // 832 KiB
  ushort_t* xin = (ushort_t*)(wsb + 16 * MB);      // 64MB (attn buffers dead)
  ushort_t* gated = (ushort_t*)(wsb + 80 * MB);    // 32MB

  const ushort_t* wb_qkv = wbuf;            // [384][128]
  const ushort_t* wb_apo = wbuf + 49152;    // [128][384]
  const ushort_t* wb_fin = wbuf + 98304;    // [1024][128]
  const ushort_t* wb_fpo = wbuf + 229376;   // [128][1536]

  const int ln_grid = (B_ * HW_) / 64;                   // 512
  const int g_qkv = B_ * (384 / 64) * 64;                // 3072
  const int g128 = B_ * (C_ / 64) * 64;                  // 1024
  const int g1024 = B_ * (1024 / 64) * 64;               // 8192
  const dim3 dwt_grid(B_ * C_ * 2, 3);                   // 2048 x 3
  const int ffg_grid = B_ * 512;                         // 4096
  const dim3 att_grid(B_ * HEADS_, 16);                  // 64 x 16

  // ---- prep ----
  hipMemsetAsync(sumsq, 0, 3 * 2048 * sizeof(float), stream);
  cvt_w<<<1664, 256, 0, stream>>>(wq, wk, wv, attn_po, ffn_in, ffn_po, wbuf);

  // ---- attention branch ----
  ln_ch<<<ln_grid, 256, 0, stream>>>(x, ln1_w, ln1_b, xnb);
  conv1x1_m<ushort_t, ushort_t><<<g_qkv, 256, 0, stream>>>(
      xnb, wb_qkv, nullptr, qkv0, C_, 384, C_, 0);

  for (int s = 0; s < 3; s++) {
    float* sumsq_s = sumsq + s * 2048;
    if (s == 0)
      dwconv_d<3><<<dwt_grid, 256, 0, stream>>>(qkv0, dw[0], dw[1], dw[2],
                                                qdb, kdb, vdb, sumsq_s);
    else if (s == 1)
      dwconv_d<5><<<dwt_grid, 256, 0, stream>>>(qkv0, dw[3], dw[4], dw[5],
                                                qdb, kdb, vdb, sumsq_s);
    else
      dwconv_d<7><<<dwt_grid, 256, 0, stream>>>(qkv0, dw[6], dw[7], dw[8],
                                                qdb, kdb, vdb, sumsq_s);
    attn_score_part<<<att_grid, 256, 0, stream>>>(qdb, kdb, part);
    attn_pv_sm<<<att_grid, 256, 0, stream>>>(vdb, part, sumsq_s, temp, osb_all,
                                             s * C_);
  }
  // single merged attn_po GEMM: x2 = x + attn_po @ osb_all (cin=384)
  conv1x1_m<ushort_t, float><<<g128, 256, 0, stream>>>(
      osb_all, wb_apo, x, x2, 384, C_, 384, 0);

  // ---- FFN branch ----
  ln_ch<<<ln_grid, 256, 0, stream>>>(x2, ln2_w, ln2_b, xnb);
  conv1x1_m<ushort_t, ushort_t><<<g1024, 256, 0, stream>>>(
      xnb, wb_fin, nullptr, xin, C_, 1024, C_, 0);

  for (int s = 0; s < 3; s++) {
    if (s == 0)
      ffn_dwgate_p<3><<<ffg_grid, 256, 0, stream>>>(xin, ffn_dw[0], gated);
    else if (s == 1)
      ffn_dwgate_p<5><<<ffg_grid, 256, 0, stream>>>(xin, ffn_dw[1], gated);
    else
      ffn_dwgate_p<7><<<ffg_grid, 256, 0, stream>>>(xin, ffn_dw[2], gated);
    conv1x1_m<ushort_t, float><<<g128, 256, 0, stream>>>(
        gated, wb_fpo + s * 512, (s == 0) ? x2 : nullptr, out, 512, C_, 3 * HID_,
        s == 0 ? 0 : 1);
  }
  (void)in_sizes; (void)n_in; (void)out_size; (void)ws_size;
}

// Round 22
// 374.257 us; speedup vs baseline: 1.2630x; 1.0569x over previous
//
#include <hip/hip_runtime.h>
#include <hip/hip_bf16.h>
#include <math.h>

#define B_ 8
#define C_ 128
#define H_ 64
#define W_ 64
#define HW_ 4096
#define HEADS_ 8
#define CH_ 16
#define HID_ 512

typedef unsigned short ushort_t;
struct __attribute__((aligned(8))) us4 { ushort_t x, y, z, w; };

typedef __attribute__((ext_vector_type(8))) short bf16x8;
typedef __attribute__((ext_vector_type(4))) float f32x4;

__device__ __forceinline__ float bf2f(ushort_t u) {
  return __uint_as_float(((unsigned int)u) << 16);
}
__device__ __forceinline__ ushort_t f2bu(float f) {
  __hip_bfloat16 h = __float2bfloat16(f);
  return *reinterpret_cast<ushort_t*>(&h);
}
__device__ __forceinline__ float toF(float v) { return v; }
__device__ __forceinline__ float toF(ushort_t v) { return bf2f(v); }
__device__ __forceinline__ void storeF(float* p, float v) { *p = v; }
__device__ __forceinline__ void storeF(ushort_t* p, float v) { *p = f2bu(v); }

// tanh-GELU: max dev from exact erf-GELU ~1e-3, straight-line
__device__ __forceinline__ float gelu_t(float x) {
  float z = 0.7978845608f * fmaf(0.044715f * x, x * x, x);
  float e = __expf(2.f * z);
  float th = 1.f - 2.f / (e + 1.f);
  return 0.5f * x * (1.f + th);
}

// ------- LayerNorm over channel dim (bf16 out), v2: 64 pos/block x 4 ch-groups -------
__global__ __launch_bounds__(256) void ln_ch(const float* __restrict__ x,
                                             const float* __restrict__ w,
                                             const float* __restrict__ b,
                                             ushort_t* __restrict__ out) {
  __shared__ float rs[4][64];
  __shared__ float rss[4][64];
  int tid = threadIdx.x;
  int pl = tid & 63;
  int cg = tid >> 6;
  int p = blockIdx.x * 64 + pl;  // over B*HW
  int bi = p >> 12;
  int pos = p & (HW_ - 1);
  const float* xb = x + (size_t)bi * C_ * HW_ + pos;
  float s = 0.f, ss = 0.f;
#pragma unroll 8
  for (int c = 0; c < 32; c++) {
    float v = xb[(size_t)(cg * 32 + c) * HW_];
    s += v;
    ss = fmaf(v, v, ss);
  }
  rs[cg][pl] = s;
  rss[cg][pl] = ss;
  __syncthreads();
  float ts = rs[0][pl] + rs[1][pl] + rs[2][pl] + rs[3][pl];
  float tss = rss[0][pl] + rss[1][pl] + rss[2][pl] + rss[3][pl];
  float mu = ts * (1.f / C_);
  float var = tss * (1.f / C_) - mu * mu;
  float inv = rsqrtf(var + 1e-5f);
  ushort_t* ob = out + (size_t)bi * C_ * HW_ + pos;
#pragma unroll 8
  for (int c = 0; c < 32; c++) {
    int ch = cg * 32 + c;
    ob[(size_t)ch * HW_] = f2bu((xb[(size_t)ch * HW_] - mu) * inv * w[ch] + b[ch]);
  }
}

// ---------------- weight prep: fp32 -> bf16, all six matrices ----------------
__global__ __launch_bounds__(256) void cvt_w(const float* __restrict__ wq,
                                             const float* __restrict__ wk,
                                             const float* __restrict__ wv,
                                             const float* __restrict__ apo,
                                             const float* __restrict__ fin,
                                             const float* __restrict__ fpo,
                                             ushort_t* __restrict__ dst) {
  int id = blockIdx.x * 256 + threadIdx.x;
  const float* src;
  int off;
  if (id < 16384) { src = wq; off = id; }
  else if (id < 32768) { src = wk; off = id - 16384; }
  else if (id < 49152) { src = wv; off = id - 32768; }
  else if (id < 98304) { src = apo; off = id - 49152; }
  else if (id < 229376) { src = fin; off = id - 98304; }
  else if (id < 425984) { src = fpo; off = id - 229376; }
  else return;
  dst[id] = f2bu(src[off]);
}

// ------- shfl-halo row load: rv[j] = row[cb-4+j], j=0..15, zero pad at edges -------
__device__ __forceinline__ void loadrow_sh(const ushort_t* __restrict__ rowp,
                                           int cb, int lane7, float* rv) {
  uint2 a = *(const uint2*)(rowp + cb);      // row[cb..cb+3]
  uint2 b = *(const uint2*)(rowp + cb + 4);  // row[cb+4..cb+7]
  unsigned l0 = __shfl_up(b.x, 1, 64);
  unsigned l1 = __shfl_up(b.y, 1, 64);
  unsigned r0 = __shfl_down(a.x, 1, 64);
  unsigned r1 = __shfl_down(a.y, 1, 64);
  if (lane7 == 0) { l0 = 0u; l1 = 0u; }
  if (lane7 == 7) { r0 = 0u; r1 = 0u; }
  rv[0]  = __uint_as_float(l0 << 16);  rv[1]  = __uint_as_float(l0 & 0xffff0000u);
  rv[2]  = __uint_as_float(l1 << 16);  rv[3]  = __uint_as_float(l1 & 0xffff0000u);
  rv[4]  = __uint_as_float(a.x << 16); rv[5]  = __uint_as_float(a.x & 0xffff0000u);
  rv[6]  = __uint_as_float(a.y << 16); rv[7]  = __uint_as_float(a.y & 0xffff0000u);
  rv[8]  = __uint_as_float(b.x << 16); rv[9]  = __uint_as_float(b.x & 0xffff0000u);
  rv[10] = __uint_as_float(b.y << 16); rv[11] = __uint_as_float(b.y & 0xffff0000u);
  rv[12] = __uint_as_float(r0 << 16);  rv[13] = __uint_as_float(r0 & 0xffff0000u);
  rv[14] = __uint_as_float(r1 << 16);  rv[15] = __uint_as_float(r1 & 0xffff0000u);
}

// ------- conv1x1 as bf16 MFMA GEMM: Out[cout][HW] = W[cout][cin] @ In[cin][HW] -------
template <typename Tin, typename Tout>
__global__ __launch_bounds__(256) void conv1x1_m(const Tin* __restrict__ in,
                                                 const ushort_t* __restrict__ wtb,
                                                 const float* __restrict__ resid,
                                                 Tout* __restrict__ out,
                                                 int cin, int cout, int wstride,
                                                 int accum) {
  constexpr int ST2 = 136;
  __shared__ ushort_t bsh[64 * ST2];
  int tid = threadIdx.x;
  int lane = tid & 63;
  int wid = tid >> 6;
  int lrow = lane & 15;
  int lk = lane >> 4;
  int blk = blockIdx.x;
  int nb = blk & 63;
  int rest = blk >> 6;
  int mb = cout >> 6;
  int m = rest % mb;
  int bi = rest / mb;
  int n0 = nb << 6;
  int o0 = (m << 6) + wid * 16;

  f32x4 acc[4] = {{0.f, 0.f, 0.f, 0.f}, {0.f, 0.f, 0.f, 0.f},
                  {0.f, 0.f, 0.f, 0.f}, {0.f, 0.f, 0.f, 0.f}};

  int nn = tid & 63;
  int wk4 = tid >> 6;
  for (int kc = 0; kc < cin; kc += 128) {
#pragma unroll
    for (int p = 0; p < 8; p++) {
      int kb = p * 16 + wk4 * 4;
      ushort_t u[4];
#pragma unroll
      for (int j = 0; j < 4; j++) {
        const Tin* src = in + ((size_t)bi * cin + kc + kb + j) * HW_ + n0 + nn;
        if constexpr (sizeof(Tin) == 4) {
          u[j] = f2bu(*(const float*)src);
        } else {
          u[j] = *(const ushort_t*)src;
        }
      }
      us4 w4;
      w4.x = u[0]; w4.y = u[1]; w4.z = u[2]; w4.w = u[3];
      *(us4*)&bsh[nn * ST2 + kb] = w4;
    }
    __syncthreads();
#pragma unroll
    for (int ks = 0; ks < 4; ks++) {
      const ushort_t* wr = wtb + (size_t)(o0 + lrow) * wstride + kc + ks * 32 + lk * 8;
      us4 wlo = *(const us4*)wr;
      us4 whi = *(const us4*)(wr + 4);
      bf16x8 af;
      af[0] = (short)wlo.x; af[1] = (short)wlo.y;
      af[2] = (short)wlo.z; af[3] = (short)wlo.w;
      af[4] = (short)whi.x; af[5] = (short)whi.y;
      af[6] = (short)whi.z; af[7] = (short)whi.w;
#pragma unroll
      for (int s = 0; s < 4; s++) {
        bf16x8 bf_ = *(const bf16x8*)&bsh[(s * 16 + lrow) * ST2 + ks * 32 + lk * 8];
        acc[s] = __builtin_amdgcn_mfma_f32_16x16x32_bf16(af, bf_, acc[s], 0, 0, 0);
      }
    }
    __syncthreads();
  }

  const float* rp = resid ? resid + (size_t)bi * cout * HW_ : nullptr;
  Tout* op = out + (size_t)bi * cout * HW_;
#pragma unroll
  for (int s = 0; s < 4; s++) {
#pragma unroll
    for (int r = 0; r < 4; r++) {
      int o = o0 + lk * 4 + r;
      int n = n0 + s * 16 + lrow;
      size_t off = (size_t)o * HW_ + n;
      float v = acc[s][r];
      if (rp) v += rp[off];
      if (accum) v += toF(op[off]);
      storeF(&op[off], v);
    }
  }
}

// ------- depthwise conv (bf16 in/out), fused L2 sum-of-squares, shfl-halo loads -------
template <int K>
__global__ __launch_bounds__(256) void dwconv_d(const ushort_t* __restrict__ qkv0,
                                                const float* __restrict__ wq_,
                                                const float* __restrict__ wk_,
                                                const float* __restrict__ wv_,
                                                ushort_t* __restrict__ qd,
                                                ushort_t* __restrict__ kd,
                                                ushort_t* __restrict__ vd,
                                                float* __restrict__ sumsq_s) {
  constexpr int P = K / 2;
  __shared__ float wsh[K * K];
  __shared__ float red[4];
  int sel = blockIdx.y;
  const float* wgt = (sel == 0) ? wq_ : (sel == 1) ? wk_ : wv_;
  ushort_t* outp = (sel == 0) ? qd : (sel == 1) ? kd : vd;
  int blk = blockIdx.x;  // B*C*2
  int half = blk & 1;
  int c = (blk >> 1) & (C_ - 1);
  int bi = blk >> 8;
  int tid = threadIdx.x;

  if (tid < K * K) wsh[tid] = wgt[(size_t)c * K * K + tid];
  __syncthreads();

  int r = tid >> 3;
  int lane7 = tid & 7;
  int cb = lane7 << 3;
  int y = half * 32 + r;
  const ushort_t* plane = qkv0 + ((size_t)bi * 384 + sel * C_ + c) * HW_;

  float a[8];
#pragma unroll
  for (int o = 0; o < 8; o++) a[o] = 0.f;
#pragma unroll
  for (int dy = 0; dy < K; dy++) {
    int gy = y + dy - P;
    if ((unsigned)gy < 64u) {
      float rv[16];
      loadrow_sh(plane + gy * 64, cb, lane7, rv);
#pragma unroll
      for (int dx = 0; dx < K; dx++) {
        float wv = wsh[dy * K + dx];
#pragma unroll
        for (int o = 0; o < 8; o++) a[o] = fmaf(rv[o + dx + 4 - P], wv, a[o]);
      }
    }
  }
  ushort_t* ob = outp + (size_t)(bi * C_ + c) * HW_ + y * 64 + cb;
  us4 t0, t1;
  t0.x = f2bu(a[0]); t0.y = f2bu(a[1]); t0.z = f2bu(a[2]); t0.w = f2bu(a[3]);
  t1.x = f2bu(a[4]); t1.y = f2bu(a[5]); t1.z = f2bu(a[6]); t1.w = f2bu(a[7]);
  *(us4*)ob = t0;
  *(us4*)(ob + 4) = t1;

  float ssq = 0.f;
#pragma unroll
  for (int o = 0; o < 8; o++) ssq = fmaf(a[o], a[o], ssq);
#pragma unroll
  for (int off = 32; off >= 1; off >>= 1) ssq += __shfl_xor(ssq, off, 64);
  if ((tid & 63) == 0) red[tid >> 6] = ssq;
  __syncthreads();
  if (tid == 0 && sel < 2) {
    atomicAdd(&sumsq_s[sel * 1024 + bi * C_ + c], red[0] + red[1] + red[2] + red[3]);
  }
}

// ------- FFN depthwise conv + GEGLU gate, 2x8 patch/thread, shfl-halo loads -------
template <int K>
__global__ __launch_bounds__(256) void ffn_dwgate_p(const ushort_t* __restrict__ xin,
                                                    const float* __restrict__ w,
                                                    ushort_t* __restrict__ gated) {
  constexpr int P = K / 2;
  __shared__ float wsh[2 * K * K];
  int blk = blockIdx.x;  // B*512
  int i = blk & 511;
  int bi = blk >> 9;
  int tid = threadIdx.x;

  if (tid < 2 * K * K) {
    wsh[tid] = (tid < K * K) ? w[(size_t)i * K * K + tid]
                             : w[(size_t)(512 + i) * K * K + (tid - K * K)];
  }
  __syncthreads();

  int r2 = tid >> 3;          // 0..31
  int lane7 = tid & 7;
  int cb = lane7 << 3;
  int y0 = r2 * 2;
  const ushort_t* gin = xin + (size_t)(bi * 1024 + i) * HW_;
  const ushort_t* min_ = gin + (size_t)512 * HW_;

  float ge[16];
  {
    float a0[8], a1[8];
#pragma unroll
    for (int o = 0; o < 8; o++) { a0[o] = 0.f; a1[o] = 0.f; }
#pragma unroll
    for (int rr = 0; rr <= K; rr++) {
      int gy = y0 - P + rr;
      if ((unsigned)gy < 64u) {
        float rv[16];
        loadrow_sh(gin + gy * 64, cb, lane7, rv);
        if (rr < K) {
          float wv;
#pragma unroll
          for (int dx = 0; dx < K; dx++) {
            wv = wsh[rr * K + dx];
#pragma unroll
            for (int o = 0; o < 8; o++) a0[o] = fmaf(rv[o + dx + 4 - P], wv, a0[o]);
          }
        }
        if (rr >= 1) {
          float wv;
#pragma unroll
          for (int dx = 0; dx < K; dx++) {
            wv = wsh[(rr - 1) * K + dx];
#pragma unroll
            for (int o = 0; o < 8; o++) a1[o] = fmaf(rv[o + dx + 4 - P], wv, a1[o]);
          }
        }
      }
    }
#pragma unroll
    for (int o = 0; o < 8; o++) { ge[o] = gelu_t(a0[o]); ge[8 + o] = gelu_t(a1[o]); }
  }

  float m0[8], m1[8];
#pragma unroll
  for (int o = 0; o < 8; o++) { m0[o] = 0.f; m1[o] = 0.f; }
#pragma unroll
  for (int rr = 0; rr <= K; rr++) {
    int gy = y0 - P + rr;
    if ((unsigned)gy < 64u) {
      float rv[16];
      loadrow_sh(min_ + gy * 64, cb, lane7, rv);
      if (rr < K) {
        float wv;
#pragma unroll
        for (int dx = 0; dx < K; dx++) {
          wv = wsh[K * K + rr * K + dx];
#pragma unroll
          for (int o = 0; o < 8; o++) m0[o] = fmaf(rv[o + dx + 4 - P], wv, m0[o]);
        }
      }
      if (rr >= 1) {
        float wv;
#pragma unroll
        for (int dx = 0; dx < K; dx++) {
          wv = wsh[K * K + (rr - 1) * K + dx];
#pragma unroll
          for (int o = 0; o < 8; o++) m1[o] = fmaf(rv[o + dx + 4 - P], wv, m1[o]);
        }
      }
    }
  }
  ushort_t* gp = gated + (size_t)(bi * 512 + i) * HW_ + y0 * 64 + cb;
#pragma unroll
  for (int v = 0; v < 2; v++) {
    us4 t;
    t.x = f2bu(ge[v * 4 + 0] * m0[v * 4 + 0]);
    t.y = f2bu(ge[v * 4 + 1] * m0[v * 4 + 1]);
    t.z = f2bu(ge[v * 4 + 2] * m0[v * 4 + 2]);
    t.w = f2bu(ge[v * 4 + 3] * m0[v * 4 + 3]);
    *(us4*)(gp + v * 4) = t;
  }
  gp += 64;
#pragma unroll
  for (int v = 0; v < 2; v++) {
    us4 t;
    t.x = f2bu(ge[8 + v * 4 + 0] * m1[v * 4 + 0]);
    t.y = f2bu(ge[8 + v * 4 + 1] * m1[v * 4 + 1]);
    t.z = f2bu(ge[8 + v * 4 + 2] * m1[v * 4 + 2]);
    t.w = f2bu(ge[8 + v * 4 + 3] * m1[v * 4 + 3]);
    *(us4*)(gp + v * 4) = t;
  }
}

// ------- attention: QK^T partial scores via MFMA (mirrors conv1x1_m layouts) -------
// S[c][d] = sum_k q[c,k]*k[d,k]: A-frag = q rows (lane&15 = c, 8 contig k at
// 8*(lane>>4)), B-frag = k rows (lane&15 = d, same k pattern). D: c=4*lk+r,
// d=lane&15 (m89-verified mapping, identical roles to conv1x1_m).
__global__ __launch_bounds__(256) void attn_score_mfma(const ushort_t* __restrict__ qd,
                                                       const ushort_t* __restrict__ kd,
                                                       float* __restrict__ part) {
  int bh = blockIdx.x;                    // 64
  int wid = threadIdx.x >> 6;             // 0..3
  int ch = blockIdx.y * 4 + wid;          // 16 chunks of 256
  int lane = threadIdx.x & 63;
  int lrow = lane & 15;
  int lk = lane >> 4;
  int bi = bh >> 3;
  int h = bh & 7;
  const ushort_t* qrow = qd + (size_t)(bi * C_ + h * CH_ + lrow) * HW_ + ch * 256;
  const ushort_t* krow = kd + (size_t)(bi * C_ + h * CH_ + lrow) * HW_ + ch * 256;

  f32x4 acc = {0.f, 0.f, 0.f, 0.f};
#pragma unroll
  for (int ks = 0; ks < 8; ks++) {
    int ko = ks * 32 + lk * 8;
    us4 qa = *(const us4*)(qrow + ko);
    us4 qb = *(const us4*)(qrow + ko + 4);
    us4 ka = *(const us4*)(krow + ko);
    us4 kb = *(const us4*)(krow + ko + 4);
    bf16x8 af, bf_;
    af[0] = (short)qa.x; af[1] = (short)qa.y; af[2] = (short)qa.z; af[3] = (short)qa.w;
    af[4] = (short)qb.x; af[5] = (short)qb.y; af[6] = (short)qb.z; af[7] = (short)qb.w;
    bf_[0] = (short)ka.x; bf_[1] = (short)ka.y; bf_[2] = (short)ka.z; bf_[3] = (short)ka.w;
    bf_[4] = (short)kb.x; bf_[5] = (short)kb.y; bf_[6] = (short)kb.z; bf_[7] = (short)kb.w;
    acc = __builtin_amdgcn_mfma_f32_16x16x32_bf16(af, bf_, acc, 0, 0, 0);
  }
  float* pp = part + ((size_t)bh * 16 + ch) * 256;
#pragma unroll
  for (int r = 0; r < 4; r++) {
    pp[(lk * 4 + r) * 16 + lrow] = acc[r];
  }
}

// ------- attention: fused softmax + PV; writes merged osb_all [bi][384][HW] -------
__global__ __launch_bounds__(256) void attn_pv_sm(const ushort_t* __restrict__ vd,
                                                  const float* __restrict__ part,
                                                  const float* __restrict__ sumsq_s,
                                                  const float* __restrict__ temp,
                                                  ushort_t* __restrict__ osb_all,
                                                  int coff) {
  __shared__ float as[16][17];
  int bh = blockIdx.x;  // 64
  int ch = blockIdx.y;  // 16
  int bi = bh >> 3;
  int h = bh & 7;
  int tid = threadIdx.x;

  {
    int c = tid >> 4;
    int d = tid & 15;
    float s = 0.f;
    const float* pp = part + (size_t)bh * 16 * 256 + tid;
#pragma unroll
    for (int c2 = 0; c2 < 16; c2++) s += pp[c2 * 256];
    float sq = sumsq_s[bi * C_ + h * CH_ + c];
    float sk = sumsq_s[1024 + bi * C_ + h * CH_ + d];
    float invq = 1.f / fmaxf(sqrtf(sq), 1e-12f);
    float invk = 1.f / fmaxf(sqrtf(sk), 1e-12f);
    float S = s * invq * invk * temp[h];
    float mx = S;
#pragma unroll
    for (int o = 8; o >= 1; o >>= 1) mx = fmaxf(mx, __shfl_xor(mx, o, 16));
    float e = expf(S - mx);
    float sm = e;
#pragma unroll
    for (int o = 8; o >= 1; o >>= 1) sm += __shfl_xor(sm, o, 16);
    as[c][d] = e / sm;
  }
  __syncthreads();

  int n = ch * 256 + tid;
  const ushort_t* vrow = vd + (size_t)(bi * C_ + h * CH_) * HW_ + n;
  float o_[16];
#pragma unroll
  for (int cc = 0; cc < 16; cc++) o_[cc] = 0.f;
#pragma unroll
  for (int dd = 0; dd < 16; dd++) {
    float vv = bf2f(vrow[(size_t)dd * HW_]);
#pragma unroll
    for (int cc = 0; cc < 16; cc++) o_[cc] = fmaf(as[cc][dd], vv, o_[cc]);
  }
  ushort_t* ob = osb_all + ((size_t)bi * 384 + coff + h * CH_) * HW_ + n;
#pragma unroll
  for (int cc = 0; cc < 16; cc++) ob[(size_t)cc * HW_] = f2bu(o_[cc]);
}

extern "C" void kernel_launch(void* const* d_in, const int* in_sizes, int n_in,
                              void* d_out, int out_size, void* d_ws, size_t ws_size,
                              hipStream_t stream) {
  const float* x = (const float*)d_in[0];
  const float* ln1_w = (const float*)d_in[1];
  const float* ln1_b = (const float*)d_in[2];
  const float* temp = (const float*)d_in[3];
  const float* wq = (const float*)d_in[4];
  const float* wk = (const float*)d_in[5];
  const float* wv = (const float*)d_in[6];
  const float* dw[9];
  for (int i = 0; i < 9; i++) dw[i] = (const float*)d_in[7 + i];
  const float* attn_po = (const float*)d_in[16];
  const float* ln2_w = (const float*)d_in[17];
  const float* ln2_b = (const float*)d_in[18];
  const float* ffn_in = (const float*)d_in[19];
  const float* ffn_dw[3] = {(const float*)d_in[20], (const float*)d_in[21],
                            (const float*)d_in[22]};
  const float* ffn_po = (const float*)d_in[23];
  float* out = (float*)d_out;

  // ---- workspace layout (bf16 intermediates), lifetime-aliased ----
  const size_t MB = (size_t)1 << 20;
  char* wsb = (char*)d_ws;
  ushort_t* xnb = (ushort_t*)(wsb + 0 * MB);
  float* part = (float*)(wsb + 0 * MB);  // 1MB; xnb dead when used
  ushort_t* qkv0 = (ushort_t*)(wsb + 16 * MB);     // 24MB
  ushort_t* qdb = (ushort_t*)(wsb + 40 * MB);      // 8MB
  ushort_t* kdb = (ushort_t*)(wsb + 48 * MB);
  ushort_t* vdb = (ushort_t*)(wsb + 56 * MB);
  ushort_t* osb_all = (ushort_t*)(wsb + 64 * MB);  // 24MB
  float* x2 = (float*)(wsb + 112 * MB);            // 16MB
  float* sumsq = (float*)(wsb + 128 * MB);                   // 24 KiB
  ushort_t* wbuf = (ushort_t*)(wsb + 128 * MB + 32 * 1024);  // 832 KiB
  ushort_t* xin = (ushort_t*)(wsb + 16 * MB);      // 64MB (attn buffers dead)
  ushort_t* gated = (ushort_t*)(wsb + 80 * MB);    // 32MB

  const ushort_t* wb_qkv = wbuf;            // [384][128]
  const ushort_t* wb_apo = wbuf + 49152;    // [128][384]
  const ushort_t* wb_fin = wbuf + 98304;    // [1024][128]
  const ushort_t* wb_fpo = wbuf + 229376;   // [128][1536]

  const int ln_grid = (B_ * HW_) / 64;                   // 512
  const int g_qkv = B_ * (384 / 64) * 64;                // 3072
  const int g128 = B_ * (C_ / 64) * 64;                  // 1024
  const int g1024 = B_ * (1024 / 64) * 64;               // 8192
  const dim3 dwt_grid(B_ * C_ * 2, 3);                   // 2048 x 3
  const int ffg_grid = B_ * 512;                         // 4096
  const dim3 score_grid(B_ * HEADS_, 4);                 // 64 x 4 (4 waves/block)
  const dim3 att_grid(B_ * HEADS_, 16);                  // 64 x 16

  // ---- prep ----
  hipMemsetAsync(sumsq, 0, 3 * 2048 * sizeof(float), stream);
  cvt_w<<<1664, 256, 0, stream>>>(wq, wk, wv, attn_po, ffn_in, ffn_po, wbuf);

  // ---- attention branch ----
  ln_ch<<<ln_grid, 256, 0, stream>>>(x, ln1_w, ln1_b, xnb);
  conv1x1_m<ushort_t, ushort_t><<<g_qkv, 256, 0, stream>>>(
      xnb, wb_qkv, nullptr, qkv0, C_, 384, C_, 0);

  for (int s = 0; s < 3; s++) {
    float* sumsq_s = sumsq + s * 2048;
    if (s == 0)
      dwconv_d<3><<<dwt_grid, 256, 0, stream>>>(qkv0, dw[0], dw[1], dw[2],
                                                qdb, kdb, vdb, sumsq_s);
    else if (s == 1)
      dwconv_d<5><<<dwt_grid, 256, 0, stream>>>(qkv0, dw[3], dw[4], dw[5],
                                                qdb, kdb, vdb, sumsq_s);
    else
      dwconv_d<7><<<dwt_grid, 256, 0, stream>>>(qkv0, dw[6], dw[7], dw[8],
                                                qdb, kdb, vdb, sumsq_s);
    attn_score_mfma<<<score_grid, 256, 0, stream>>>(qdb, kdb, part);
    attn_pv_sm<<<att_grid, 256, 0, stream>>>(vdb, part, sumsq_s, temp, osb_all,
                                             s * C_);
  }
  // single merged attn_po GEMM: x2 = x + attn_po @ osb_all (cin=384)
  conv1x1_m<ushort_t, float><<<g128, 256, 0, stream>>>(
      osb_all, wb_apo, x, x2, 384, C_, 384, 0);

  // ---- FFN branch ----
  ln_ch<<<ln_grid, 256, 0, stream>>>(x2, ln2_w, ln2_b, xnb);
  conv1x1_m<ushort_t, ushort_t><<<g1024, 256, 0, stream>>>(
      xnb, wb_fin, nullptr, xin, C_, 1024, C_, 0);

  for (int s = 0; s < 3; s++) {
    if (s == 0)
      ffn_dwgate_p<3><<<ffg_grid, 256, 0, stream>>>(xin, ffn_dw[0], gated);
    else if (s == 1)
      ffn_dwgate_p<5><<<ffg_grid, 256, 0, stream>>>(xin, ffn_dw[1], gated);
    else
      ffn_dwgate_p<7><<<ffg_grid, 256, 0, stream>>>(xin, ffn_dw[2], gated);
    conv1x1_m<ushort_t, float><<<g128, 256, 0, stream>>>(
        gated, wb_fpo + s * 512, (s == 0) ? x2 : nullptr, out, 512, C_, 3 * HID_,
        s == 0 ? 0 : 1);
  }
  (void)in_sizes; (void)n_in; (void)out_size; (void)ws_size;
}

// Round 23
// 368.905 us; speedup vs baseline: 1.2813x; 1.0145x over previous
//
#include <hip/hip_runtime.h>
#include <hip/hip_bf16.h>
#include <math.h>

#define B_ 8
#define C_ 128
#define H_ 64
#define W_ 64
#define HW_ 4096
#define HEADS_ 8
#define CH_ 16
#define HID_ 512

typedef unsigned short ushort_t;
struct __attribute__((aligned(8))) us4 { ushort_t x, y, z, w; };

typedef __attribute__((ext_vector_type(8))) short bf16x8;
typedef __attribute__((ext_vector_type(4))) float f32x4;

__device__ __forceinline__ float bf2f(ushort_t u) {
  return __uint_as_float(((unsigned int)u) << 16);
}
__device__ __forceinline__ ushort_t f2bu(float f) {
  __hip_bfloat16 h = __float2bfloat16(f);
  return *reinterpret_cast<ushort_t*>(&h);
}
__device__ __forceinline__ float toF(float v) { return v; }
__device__ __forceinline__ float toF(ushort_t v) { return bf2f(v); }
__device__ __forceinline__ void storeF(float* p, float v) { *p = v; }
__device__ __forceinline__ void storeF(ushort_t* p, float v) { *p = f2bu(v); }

// tanh-GELU: max dev from exact erf-GELU ~1e-3, straight-line
__device__ __forceinline__ float gelu_t(float x) {
  float z = 0.7978845608f * fmaf(0.044715f * x, x * x, x);
  float e = __expf(2.f * z);
  float th = 1.f - 2.f / (e + 1.f);
  return 0.5f * x * (1.f + th);
}

// ------- LayerNorm over channel dim (bf16 out), v2: 64 pos/block x 4 ch-groups -------
__global__ __launch_bounds__(256) void ln_ch(const float* __restrict__ x,
                                             const float* __restrict__ w,
                                             const float* __restrict__ b,
                                             ushort_t* __restrict__ out) {
  __shared__ float rs[4][64];
  __shared__ float rss[4][64];
  int tid = threadIdx.x;
  int pl = tid & 63;
  int cg = tid >> 6;
  int p = blockIdx.x * 64 + pl;  // over B*HW
  int bi = p >> 12;
  int pos = p & (HW_ - 1);
  const float* xb = x + (size_t)bi * C_ * HW_ + pos;
  float s = 0.f, ss = 0.f;
#pragma unroll 8
  for (int c = 0; c < 32; c++) {
    float v = xb[(size_t)(cg * 32 + c) * HW_];
    s += v;
    ss = fmaf(v, v, ss);
  }
  rs[cg][pl] = s;
  rss[cg][pl] = ss;
  __syncthreads();
  float ts = rs[0][pl] + rs[1][pl] + rs[2][pl] + rs[3][pl];
  float tss = rss[0][pl] + rss[1][pl] + rss[2][pl] + rss[3][pl];
  float mu = ts * (1.f / C_);
  float var = tss * (1.f / C_) - mu * mu;
  float inv = rsqrtf(var + 1e-5f);
  ushort_t* ob = out + (size_t)bi * C_ * HW_ + pos;
#pragma unroll 8
  for (int c = 0; c < 32; c++) {
    int ch = cg * 32 + c;
    ob[(size_t)ch * HW_] = f2bu((xb[(size_t)ch * HW_] - mu) * inv * w[ch] + b[ch]);
  }
}

// ---------------- weight prep: fp32 -> bf16, all six matrices ----------------
__global__ __launch_bounds__(256) void cvt_w(const float* __restrict__ wq,
                                             const float* __restrict__ wk,
                                             const float* __restrict__ wv,
                                             const float* __restrict__ apo,
                                             const float* __restrict__ fin,
                                             const float* __restrict__ fpo,
                                             ushort_t* __restrict__ dst) {
  int id = blockIdx.x * 256 + threadIdx.x;
  const float* src;
  int off;
  if (id < 16384) { src = wq; off = id; }
  else if (id < 32768) { src = wk; off = id - 16384; }
  else if (id < 49152) { src = wv; off = id - 32768; }
  else if (id < 98304) { src = apo; off = id - 49152; }
  else if (id < 229376) { src = fin; off = id - 98304; }
  else if (id < 425984) { src = fpo; off = id - 229376; }
  else return;
  dst[id] = f2bu(src[off]);
}

// ------- shfl-halo row load: rv[j] = row[cb-4+j], j=0..15, zero pad at edges -------
__device__ __forceinline__ void loadrow_sh(const ushort_t* __restrict__ rowp,
                                           int cb, int lane7, float* rv) {
  uint2 a = *(const uint2*)(rowp + cb);      // row[cb..cb+3]
  uint2 b = *(const uint2*)(rowp + cb + 4);  // row[cb+4..cb+7]
  unsigned l0 = __shfl_up(b.x, 1, 64);
  unsigned l1 = __shfl_up(b.y, 1, 64);
  unsigned r0 = __shfl_down(a.x, 1, 64);
  unsigned r1 = __shfl_down(a.y, 1, 64);
  if (lane7 == 0) { l0 = 0u; l1 = 0u; }
  if (lane7 == 7) { r0 = 0u; r1 = 0u; }
  rv[0]  = __uint_as_float(l0 << 16);  rv[1]  = __uint_as_float(l0 & 0xffff0000u);
  rv[2]  = __uint_as_float(l1 << 16);  rv[3]  = __uint_as_float(l1 & 0xffff0000u);
  rv[4]  = __uint_as_float(a.x << 16); rv[5]  = __uint_as_float(a.x & 0xffff0000u);
  rv[6]  = __uint_as_float(a.y << 16); rv[7]  = __uint_as_float(a.y & 0xffff0000u);
  rv[8]  = __uint_as_float(b.x << 16); rv[9]  = __uint_as_float(b.x & 0xffff0000u);
  rv[10] = __uint_as_float(b.y << 16); rv[11] = __uint_as_float(b.y & 0xffff0000u);
  rv[12] = __uint_as_float(r0 << 16);  rv[13] = __uint_as_float(r0 & 0xffff0000u);
  rv[14] = __uint_as_float(r1 << 16);  rv[15] = __uint_as_float(r1 & 0xffff0000u);
}

// ------- conv1x1 as bf16 MFMA GEMM: Out[cout][HW] = W[cout][cin] @ In[cin][HW] -------
template <typename Tin, typename Tout>
__global__ __launch_bounds__(256) void conv1x1_m(const Tin* __restrict__ in,
                                                 const ushort_t* __restrict__ wtb,
                                                 const float* __restrict__ resid,
                                                 Tout* __restrict__ out,
                                                 int cin, int cout, int wstride,
                                                 int accum) {
  constexpr int ST2 = 136;
  __shared__ ushort_t bsh[64 * ST2];
  int tid = threadIdx.x;
  int lane = tid & 63;
  int wid = tid >> 6;
  int lrow = lane & 15;
  int lk = lane >> 4;
  int blk = blockIdx.x;
  int nb = blk & 63;
  int rest = blk >> 6;
  int mb = cout >> 6;
  int m = rest % mb;
  int bi = rest / mb;
  int n0 = nb << 6;
  int o0 = (m << 6) + wid * 16;

  f32x4 acc[4] = {{0.f, 0.f, 0.f, 0.f}, {0.f, 0.f, 0.f, 0.f},
                  {0.f, 0.f, 0.f, 0.f}, {0.f, 0.f, 0.f, 0.f}};

  int nn = tid & 63;
  int wk4 = tid >> 6;
  for (int kc = 0; kc < cin; kc += 128) {
#pragma unroll
    for (int p = 0; p < 8; p++) {
      int kb = p * 16 + wk4 * 4;
      ushort_t u[4];
#pragma unroll
      for (int j = 0; j < 4; j++) {
        const Tin* src = in + ((size_t)bi * cin + kc + kb + j) * HW_ + n0 + nn;
        if constexpr (sizeof(Tin) == 4) {
          u[j] = f2bu(*(const float*)src);
        } else {
          u[j] = *(const ushort_t*)src;
        }
      }
      us4 w4;
      w4.x = u[0]; w4.y = u[1]; w4.z = u[2]; w4.w = u[3];
      *(us4*)&bsh[nn * ST2 + kb] = w4;
    }
    __syncthreads();
#pragma unroll
    for (int ks = 0; ks < 4; ks++) {
      const ushort_t* wr = wtb + (size_t)(o0 + lrow) * wstride + kc + ks * 32 + lk * 8;
      us4 wlo = *(const us4*)wr;
      us4 whi = *(const us4*)(wr + 4);
      bf16x8 af;
      af[0] = (short)wlo.x; af[1] = (short)wlo.y;
      af[2] = (short)wlo.z; af[3] = (short)wlo.w;
      af[4] = (short)whi.x; af[5] = (short)whi.y;
      af[6] = (short)whi.z; af[7] = (short)whi.w;
#pragma unroll
      for (int s = 0; s < 4; s++) {
        bf16x8 bf_ = *(const bf16x8*)&bsh[(s * 16 + lrow) * ST2 + ks * 32 + lk * 8];
        acc[s] = __builtin_amdgcn_mfma_f32_16x16x32_bf16(af, bf_, acc[s], 0, 0, 0);
      }
    }
    __syncthreads();
  }

  const float* rp = resid ? resid + (size_t)bi * cout * HW_ : nullptr;
  Tout* op = out + (size_t)bi * cout * HW_;
#pragma unroll
  for (int s = 0; s < 4; s++) {
#pragma unroll
    for (int r = 0; r < 4; r++) {
      int o = o0 + lk * 4 + r;
      int n = n0 + s * 16 + lrow;
      size_t off = (size_t)o * HW_ + n;
      float v = acc[s][r];
      if (rp) v += rp[off];
      if (accum) v += toF(op[off]);
      storeF(&op[off], v);
    }
  }
}

// ------- depthwise conv (bf16 in/out), fused L2 sum-of-squares, shfl-halo loads -------
template <int K>
__global__ __launch_bounds__(256) void dwconv_d(const ushort_t* __restrict__ qkv0,
                                                const float* __restrict__ wq_,
                                                const float* __restrict__ wk_,
                                                const float* __restrict__ wv_,
                                                ushort_t* __restrict__ qd,
                                                ushort_t* __restrict__ kd,
                                                ushort_t* __restrict__ vd,
                                                float* __restrict__ sumsq_s) {
  constexpr int P = K / 2;
  __shared__ float wsh[K * K];
  __shared__ float red[4];
  int sel = blockIdx.y;
  const float* wgt = (sel == 0) ? wq_ : (sel == 1) ? wk_ : wv_;
  ushort_t* outp = (sel == 0) ? qd : (sel == 1) ? kd : vd;
  int blk = blockIdx.x;  // B*C*2
  int half = blk & 1;
  int c = (blk >> 1) & (C_ - 1);
  int bi = blk >> 8;
  int tid = threadIdx.x;

  if (tid < K * K) wsh[tid] = wgt[(size_t)c * K * K + tid];
  __syncthreads();

  int r = tid >> 3;
  int lane7 = tid & 7;
  int cb = lane7 << 3;
  int y = half * 32 + r;
  const ushort_t* plane = qkv0 + ((size_t)bi * 384 + sel * C_ + c) * HW_;

  float a[8];
#pragma unroll
  for (int o = 0; o < 8; o++) a[o] = 0.f;
#pragma unroll
  for (int dy = 0; dy < K; dy++) {
    int gy = y + dy - P;
    if ((unsigned)gy < 64u) {
      float rv[16];
      loadrow_sh(plane + gy * 64, cb, lane7, rv);
#pragma unroll
      for (int dx = 0; dx < K; dx++) {
        float wv = wsh[dy * K + dx];
#pragma unroll
        for (int o = 0; o < 8; o++) a[o] = fmaf(rv[o + dx + 4 - P], wv, a[o]);
      }
    }
  }
  ushort_t* ob = outp + (size_t)(bi * C_ + c) * HW_ + y * 64 + cb;
  us4 t0, t1;
  t0.x = f2bu(a[0]); t0.y = f2bu(a[1]); t0.z = f2bu(a[2]); t0.w = f2bu(a[3]);
  t1.x = f2bu(a[4]); t1.y = f2bu(a[5]); t1.z = f2bu(a[6]); t1.w = f2bu(a[7]);
  *(us4*)ob = t0;
  *(us4*)(ob + 4) = t1;

  float ssq = 0.f;
#pragma unroll
  for (int o = 0; o < 8; o++) ssq = fmaf(a[o], a[o], ssq);
#pragma unroll
  for (int off = 32; off >= 1; off >>= 1) ssq += __shfl_xor(ssq, off, 64);
  if ((tid & 63) == 0) red[tid >> 6] = ssq;
  __syncthreads();
  if (tid == 0 && sel < 2) {
    atomicAdd(&sumsq_s[sel * 1024 + bi * C_ + c], red[0] + red[1] + red[2] + red[3]);
  }
}

// ------- FFN depthwise conv + GEGLU gate, 2x8 patch/thread, shfl-halo loads -------
template <int K>
__global__ __launch_bounds__(256) void ffn_dwgate_p(const ushort_t* __restrict__ xin,
                                                    const float* __restrict__ w,
                                                    ushort_t* __restrict__ gated) {
  constexpr int P = K / 2;
  __shared__ float wsh[2 * K * K];
  int blk = blockIdx.x;  // B*512
  int i = blk & 511;
  int bi = blk >> 9;
  int tid = threadIdx.x;

  if (tid < 2 * K * K) {
    wsh[tid] = (tid < K * K) ? w[(size_t)i * K * K + tid]
                             : w[(size_t)(512 + i) * K * K + (tid - K * K)];
  }
  __syncthreads();

  int r2 = tid >> 3;          // 0..31
  int lane7 = tid & 7;
  int cb = lane7 << 3;
  int y0 = r2 * 2;
  const ushort_t* gin = xin + (size_t)(bi * 1024 + i) * HW_;
  const ushort_t* min_ = gin + (size_t)512 * HW_;

  float ge[16];
  {
    float a0[8], a1[8];
#pragma unroll
    for (int o = 0; o < 8; o++) { a0[o] = 0.f; a1[o] = 0.f; }
#pragma unroll
    for (int rr = 0; rr <= K; rr++) {
      int gy = y0 - P + rr;
      if ((unsigned)gy < 64u) {
        float rv[16];
        loadrow_sh(gin + gy * 64, cb, lane7, rv);
        if (rr < K) {
          float wv;
#pragma unroll
          for (int dx = 0; dx < K; dx++) {
            wv = wsh[rr * K + dx];
#pragma unroll
            for (int o = 0; o < 8; o++) a0[o] = fmaf(rv[o + dx + 4 - P], wv, a0[o]);
          }
        }
        if (rr >= 1) {
          float wv;
#pragma unroll
          for (int dx = 0; dx < K; dx++) {
            wv = wsh[(rr - 1) * K + dx];
#pragma unroll
            for (int o = 0; o < 8; o++) a1[o] = fmaf(rv[o + dx + 4 - P], wv, a1[o]);
          }
        }
      }
    }
#pragma unroll
    for (int o = 0; o < 8; o++) { ge[o] = gelu_t(a0[o]); ge[8 + o] = gelu_t(a1[o]); }
  }

  float m0[8], m1[8];
#pragma unroll
  for (int o = 0; o < 8; o++) { m0[o] = 0.f; m1[o] = 0.f; }
#pragma unroll
  for (int rr = 0; rr <= K; rr++) {
    int gy = y0 - P + rr;
    if ((unsigned)gy < 64u) {
      float rv[16];
      loadrow_sh(min_ + gy * 64, cb, lane7, rv);
      if (rr < K) {
        float wv;
#pragma unroll
        for (int dx = 0; dx < K; dx++) {
          wv = wsh[K * K + rr * K + dx];
#pragma unroll
          for (int o = 0; o < 8; o++) m0[o] = fmaf(rv[o + dx + 4 - P], wv, m0[o]);
        }
      }
      if (rr >= 1) {
        float wv;
#pragma unroll
        for (int dx = 0; dx < K; dx++) {
          wv = wsh[K * K + (rr - 1) * K + dx];
#pragma unroll
          for (int o = 0; o < 8; o++) m1[o] = fmaf(rv[o + dx + 4 - P], wv, m1[o]);
        }
      }
    }
  }
  ushort_t* gp = gated + (size_t)(bi * 512 + i) * HW_ + y0 * 64 + cb;
#pragma unroll
  for (int v = 0; v < 2; v++) {
    us4 t;
    t.x = f2bu(ge[v * 4 + 0] * m0[v * 4 + 0]);
    t.y = f2bu(ge[v * 4 + 1] * m0[v * 4 + 1]);
    t.z = f2bu(ge[v * 4 + 2] * m0[v * 4 + 2]);
    t.w = f2bu(ge[v * 4 + 3] * m0[v * 4 + 3]);
    *(us4*)(gp + v * 4) = t;
  }
  gp += 64;
#pragma unroll
  for (int v = 0; v < 2; v++) {
    us4 t;
    t.x = f2bu(ge[8 + v * 4 + 0] * m1[v * 4 + 0]);
    t.y = f2bu(ge[8 + v * 4 + 1] * m1[v * 4 + 1]);
    t.z = f2bu(ge[8 + v * 4 + 2] * m1[v * 4 + 2]);
    t.w = f2bu(ge[8 + v * 4 + 3] * m1[v * 4 + 3]);
    *(us4*)(gp + v * 4) = t;
  }
}

// ------- attention: QK^T partial scores via MFMA (R22-proven) -------
__global__ __launch_bounds__(256) void attn_score_mfma(const ushort_t* __restrict__ qd,
                                                       const ushort_t* __restrict__ kd,
                                                       float* __restrict__ part) {
  int bh = blockIdx.x;                    // 64
  int wid = threadIdx.x >> 6;             // 0..3
  int ch = blockIdx.y * 4 + wid;          // 16 chunks of 256
  int lane = threadIdx.x & 63;
  int lrow = lane & 15;
  int lk = lane >> 4;
  int bi = bh >> 3;
  int h = bh & 7;
  const ushort_t* qrow = qd + (size_t)(bi * C_ + h * CH_ + lrow) * HW_ + ch * 256;
  const ushort_t* krow = kd + (size_t)(bi * C_ + h * CH_ + lrow) * HW_ + ch * 256;

  f32x4 acc = {0.f, 0.f, 0.f, 0.f};
#pragma unroll
  for (int ks = 0; ks < 8; ks++) {
    int ko = ks * 32 + lk * 8;
    us4 qa = *(const us4*)(qrow + ko);
    us4 qb = *(const us4*)(qrow + ko + 4);
    us4 ka = *(const us4*)(krow + ko);
    us4 kb = *(const us4*)(krow + ko + 4);
    bf16x8 af, bf_;
    af[0] = (short)qa.x; af[1] = (short)qa.y; af[2] = (short)qa.z; af[3] = (short)qa.w;
    af[4] = (short)qb.x; af[5] = (short)qb.y; af[6] = (short)qb.z; af[7] = (short)qb.w;
    bf_[0] = (short)ka.x; bf_[1] = (short)ka.y; bf_[2] = (short)ka.z; bf_[3] = (short)ka.w;
    bf_[4] = (short)kb.x; bf_[5] = (short)kb.y; bf_[6] = (short)kb.z; bf_[7] = (short)kb.w;
    acc = __builtin_amdgcn_mfma_f32_16x16x32_bf16(af, bf_, acc, 0, 0, 0);
  }
  float* pp = part + ((size_t)bh * 16 + ch) * 256;
#pragma unroll
  for (int r = 0; r < 4; r++) {
    pp[(lk * 4 + r) * 16 + lrow] = acc[r];
  }
}

// ------- attention: fused softmax + PV via MFMA -------
// O[c][n] = sum_d P[c][d] V[d][n], K=16 zero-padded to 32. A-frag = P rows
// (lrow=c, k=d at lk*8, zero for lk>=2); B-frag = V^T LDS [n][d] (ST=24 elems:
// b128 16B-aligned, 2-way banks); D: c=4*lk+r, n=lrow (same verified mapping
// as conv1x1_m / attn_score_mfma). Staging: 4 scalar global loads -> ds_write_b64.
__global__ __launch_bounds__(256) void attn_pv_sm(const ushort_t* __restrict__ vd,
                                                  const float* __restrict__ part,
                                                  const float* __restrict__ sumsq_s,
                                                  const float* __restrict__ temp,
                                                  ushort_t* __restrict__ osb_all,
                                                  int coff) {
  constexpr int VST = 24;  // elems per n-row (16 d + 8 pad)
  __shared__ float as[16][17];
  __shared__ ushort_t vt[256 * VST];  // 12 KB
  int bh = blockIdx.x;  // 64
  int ch = blockIdx.y;  // 16
  int bi = bh >> 3;
  int h = bh & 7;
  int tid = threadIdx.x;
  int n0 = ch * 256;

  // ---- softmax (unchanged math) ----
  {
    int c = tid >> 4;
    int d = tid & 15;
    float s = 0.f;
    const float* pp = part + (size_t)bh * 16 * 256 + tid;
#pragma unroll
    for (int c2 = 0; c2 < 16; c2++) s += pp[c2 * 256];
    float sq = sumsq_s[bi * C_ + h * CH_ + c];
    float sk = sumsq_s[1024 + bi * C_ + h * CH_ + d];
    float invq = 1.f / fmaxf(sqrtf(sq), 1e-12f);
    float invk = 1.f / fmaxf(sqrtf(sk), 1e-12f);
    float S = s * invq * invk * temp[h];
    float mx = S;
#pragma unroll
    for (int o = 8; o >= 1; o >>= 1) mx = fmaxf(mx, __shfl_xor(mx, o, 16));
    float e = expf(S - mx);
    float sm = e;
#pragma unroll
    for (int o = 8; o >= 1; o >>= 1) sm += __shfl_xor(sm, o, 16);
    as[c][d] = e / sm;
  }

  // ---- stage V^T: vt[n][d], d contiguous ----
  {
    const ushort_t* vb = vd + (size_t)(bi * C_ + h * CH_) * HW_ + n0 + tid;
#pragma unroll
    for (int dq = 0; dq < 4; dq++) {
      us4 w4;
      w4.x = vb[(size_t)(dq * 4 + 0) * HW_];
      w4.y = vb[(size_t)(dq * 4 + 1) * HW_];
      w4.z = vb[(size_t)(dq * 4 + 2) * HW_];
      w4.w = vb[(size_t)(dq * 4 + 3) * HW_];
      *(us4*)&vt[tid * VST + dq * 4] = w4;
    }
  }
  __syncthreads();

  int wid = tid >> 6;
  int lane = tid & 63;
  int lrow = lane & 15;
  int lk = lane >> 4;

  // A-frag: P[c=lrow][d=lk*8+j], zero for lk>=2 (K padded 16->32)
  bf16x8 paf = {0, 0, 0, 0, 0, 0, 0, 0};
  if (lk < 2) {
#pragma unroll
    for (int j = 0; j < 8; j++) paf[j] = (short)f2bu(as[lrow][lk * 8 + j]);
  }

  ushort_t* ob = osb_all + ((size_t)bi * 384 + coff + h * CH_) * HW_ + n0;
#pragma unroll
  for (int m = 0; m < 4; m++) {
    int g = wid * 4 + m;  // n-group 0..15
    bf16x8 bfv = {0, 0, 0, 0, 0, 0, 0, 0};
    if (lk < 2) {
      bfv = *(const bf16x8*)&vt[(g * 16 + lrow) * VST + lk * 8];
    }
    f32x4 acc = {0.f, 0.f, 0.f, 0.f};
    acc = __builtin_amdgcn_mfma_f32_16x16x32_bf16(paf, bfv, acc, 0, 0, 0);
    int n = g * 16 + lrow;
#pragma unroll
    for (int r = 0; r < 4; r++) {
      int c = lk * 4 + r;
      ob[(size_t)c * HW_ + n] = f2bu(acc[r]);
    }
  }
}

extern "C" void kernel_launch(void* const* d_in, const int* in_sizes, int n_in,
                              void* d_out, int out_size, void* d_ws, size_t ws_size,
                              hipStream_t stream) {
  const float* x = (const float*)d_in[0];
  const float* ln1_w = (const float*)d_in[1];
  const float* ln1_b = (const float*)d_in[2];
  const float* temp = (const float*)d_in[3];
  const float* wq = (const float*)d_in[4];
  const float* wk = (const float*)d_in[5];
  const float* wv = (const float*)d_in[6];
  const float* dw[9];
  for (int i = 0; i < 9; i++) dw[i] = (const float*)d_in[7 + i];
  const float* attn_po = (const float*)d_in[16];
  const float* ln2_w = (const float*)d_in[17];
  const float* ln2_b = (const float*)d_in[18];
  const float* ffn_in = (const float*)d_in[19];
  const float* ffn_dw[3] = {(const float*)d_in[20], (const float*)d_in[21],
                            (const float*)d_in[22]};
  const float* ffn_po = (const float*)d_in[23];
  float* out = (float*)d_out;

  // ---- workspace layout (bf16 intermediates), lifetime-aliased ----
  const size_t MB = (size_t)1 << 20;
  char* wsb = (char*)d_ws;
  ushort_t* xnb = (ushort_t*)(wsb + 0 * MB);
  float* part = (float*)(wsb + 0 * MB);  // 1MB; xnb dead when used
  ushort_t* qkv0 = (ushort_t*)(wsb + 16 * MB);     // 24MB
  ushort_t* qdb = (ushort_t*)(wsb + 40 * MB);      // 8MB
  ushort_t* kdb = (ushort_t*)(wsb + 48 * MB);
  ushort_t* vdb = (ushort_t*)(wsb + 56 * MB);
  ushort_t* osb_all = (ushort_t*)(wsb + 64 * MB);  // 24MB
  float* x2 = (float*)(wsb + 112 * MB);            // 16MB
  float* sumsq = (float*)(wsb + 128 * MB);                   // 24 KiB
  ushort_t* wbuf = (ushort_t*)(wsb + 128 * MB + 32 * 1024);  // 832 KiB
  ushort_t* xin = (ushort_t*)(wsb + 16 * MB);      // 64MB (attn buffers dead)
  ushort_t* gated = (ushort_t*)(wsb + 80 * MB);    // 32MB

  const ushort_t* wb_qkv = wbuf;            // [384][128]
  const ushort_t* wb_apo = wbuf + 49152;    // [128][384]
  const ushort_t* wb_fin = wbuf + 98304;    // [1024][128]
  const ushort_t* wb_fpo = wbuf + 229376;   // [128][1536]

  const int ln_grid = (B_ * HW_) / 64;                   // 512
  const int g_qkv = B_ * (384 / 64) * 64;                // 3072
  const int g128 = B_ * (C_ / 64) * 64;                  // 1024
  const int g1024 = B_ * (1024 / 64) * 64;               // 8192
  const dim3 dwt_grid(B_ * C_ * 2, 3);                   // 2048 x 3
  const int ffg_grid = B_ * 512;                         // 4096
  const dim3 score_grid(B_ * HEADS_, 4);                 // 64 x 4
  const dim3 att_grid(B_ * HEADS_, 16);                  // 64 x 16

  // ---- prep ----
  hipMemsetAsync(sumsq, 0, 3 * 2048 * sizeof(float), stream);
  cvt_w<<<1664, 256, 0, stream>>>(wq, wk, wv, attn_po, ffn_in, ffn_po, wbuf);

  // ---- attention branch ----
  ln_ch<<<ln_grid, 256, 0, stream>>>(x, ln1_w, ln1_b, xnb);
  conv1x1_m<ushort_t, ushort_t><<<g_qkv, 256, 0, stream>>>(
      xnb, wb_qkv, nullptr, qkv0, C_, 384, C_, 0);

  for (int s = 0; s < 3; s++) {
    float* sumsq_s = sumsq + s * 2048;
    if (s == 0)
      dwconv_d<3><<<dwt_grid, 256, 0, stream>>>(qkv0, dw[0], dw[1], dw[2],
                                                qdb, kdb, vdb, sumsq_s);
    else if (s == 1)
      dwconv_d<5><<<dwt_grid, 256, 0, stream>>>(qkv0, dw[3], dw[4], dw[5],
                                                qdb, kdb, vdb, sumsq_s);
    else
      dwconv_d<7><<<dwt_grid, 256, 0, stream>>>(qkv0, dw[6], dw[7], dw[8],
                                                qdb, kdb, vdb, sumsq_s);
    attn_score_mfma<<<score_grid, 256, 0, stream>>>(qdb, kdb, part);
    attn_pv_sm<<<att_grid, 256, 0, stream>>>(vdb, part, sumsq_s, temp, osb_all,
                                             s * C_);
  }
  // single merged attn_po GEMM: x2 = x + attn_po @ osb_all (cin=384)
  conv1x1_m<ushort_t, float><<<g128, 256, 0, stream>>>(
      osb_all, wb_apo, x, x2, 384, C_, 384, 0);

  // ---- FFN branch ----
  ln_ch<<<ln_grid, 256, 0, stream>>>(x2, ln2_w, ln2_b, xnb);
  conv1x1_m<ushort_t, ushort_t><<<g1024, 256, 0, stream>>>(
      xnb, wb_fin, nullptr, xin, C_, 1024, C_, 0);

  for (int s = 0; s < 3; s++) {
    if (s == 0)
      ffn_dwgate_p<3><<<ffg_grid, 256, 0, stream>>>(xin, ffn_dw[0], gated);
    else if (s == 1)
      ffn_dwgate_p<5><<<ffg_grid, 256, 0, stream>>>(xin, ffn_dw[1], gated);
    else
      ffn_dwgate_p<7><<<ffg_grid, 256, 0, stream>>>(xin, ffn_dw[2], gated);
    conv1x1_m<ushort_t, float><<<g128, 256, 0, stream>>>(
        gated, wb_fpo + s * 512, (s == 0) ? x2 : nullptr, out, 512, C_, 3 * HID_,
        s == 0 ? 0 : 1);
  }
  (void)in_sizes; (void)n_in; (void)out_size; (void)ws_size;
}